// Round 1
// 598.827 us; speedup vs baseline: 1.0064x; 1.0064x over previous
//
#include <hip/hip_runtime.h>
#include <stdint.h>

typedef unsigned short u16;
typedef __bf16 bf16x8 __attribute__((ext_vector_type(8)));
typedef float f32x4 __attribute__((ext_vector_type(4)));

// f32 inputs/outputs (verified R2). GEMMs run bf16 MFMA (absmax 0.0156 << 0.05).
// R4 lessons: (1) dynamic acc index forced by un-unrolled phase loop, (2) 8-way
// LDS conflicts from row*32+kq layout, (3) 2 blocks/CU occupancy cap.
// R5: T3+T4 pipeline — triple-buffered LDS, depth-2 prefetch, counted vmcnt
// (never 0 in steady state), raw s_barrier + explicit lgkmcnt(0). setprio on MFMA.

__device__ __forceinline__ float bf2f(unsigned u) { return __uint_as_float(u << 16); }
__device__ __forceinline__ u16 f2bf(float f) {
  unsigned x = __float_as_uint(f);
  unsigned r = x + 0x7fffu + ((x >> 16) & 1u);
  return (u16)(r >> 16);
}
__device__ __forceinline__ unsigned pack2(float a, float b) {
  return (unsigned)f2bf(a) | ((unsigned)f2bf(b) << 16);
}
__device__ __forceinline__ float sigm(float x) { return 1.f / (1.f + __expf(-x)); }
__device__ __forceinline__ float fast_tanh(float x) {
  float e = __expf(2.f * x);
  return 1.f - 2.f / (e + 1.f);
}

#define AS1(p) ((const __attribute__((address_space(1))) void*)(p))
#define AS3(p) ((__attribute__((address_space(3))) void*)(p))

#define NC 16384

// =====================================================================
// prep: [0,16384) hid f32->bf16 cvt ; [16384,17632) weight transposes ;
// [17632,17706) smalls (bias1/bias2/counts). One launch.
// =====================================================================
__device__ __forceinline__ void packT_body(
    const float* __restrict__ src, int sld, int srow0,
    u16* __restrict__ dst, int dld, int drow0, int koff,
    int remapThresh, int remapAdd, float sgn, int bx, int by,
    float (*tile)[65], int t) {
  const int k0 = by * 64, c0 = bx * 64;
  const int tx = t & 15, ty = t >> 4;
#pragma unroll
  for (int p = 0; p < 4; ++p) {
    int r = ty + p * 16;
    float4 v = *reinterpret_cast<const float4*>(&src[(size_t)(srow0 + k0 + r) * sld + c0 + tx * 4]);
    tile[tx * 4 + 0][r] = v.x;
    tile[tx * 4 + 1][r] = v.y;
    tile[tx * 4 + 2][r] = v.z;
    tile[tx * 4 + 3][r] = v.w;
  }
  __syncthreads();
  const int cl = t >> 2;
  const int kb = (t & 3) * 16;
  int col = c0 + cl;
  int row = drow0 + col + ((col >= remapThresh) ? remapAdd : 0);
  union { u16 o[16]; uint4 v[2]; } u;
#pragma unroll
  for (int e = 0; e < 16; ++e) u.o[e] = f2bf(sgn * tile[cl][kb + e]);
  uint4* d = reinterpret_cast<uint4*>(&dst[(size_t)row * dld + koff + k0 + kb]);
  d[0] = u.v[0]; d[1] = u.v[1];
}

__global__ __launch_bounds__(256) void prep_kernel(
    const float* __restrict__ hid, u16* __restrict__ hidc,
    const float* __restrict__ W_ih, const float* __restrict__ W_hh, u16* __restrict__ WgruT,
    const float* __restrict__ Wa1, const float* __restrict__ Wg1, u16* __restrict__ W1catT,
    const float* __restrict__ Wa2, const float* __restrict__ Wg2, u16* __restrict__ W2catT,
    const float* __restrict__ x, const float* __restrict__ ba1, const float* __restrict__ bg1,
    float* __restrict__ bias1, const float* __restrict__ ba2, const float* __restrict__ bg2,
    float* __restrict__ bias2, const int* __restrict__ positions, int* __restrict__ counts) {
  __shared__ float tile[64][65];
  int b = blockIdx.x, t = threadIdx.x;
  if (b < 16384) {  // cvt: 4 f32 -> 4 bf16 per thread, fully coalesced
    int i = b * 256 + t;
    float4 v = ((const float4*)hid)[i];
    uint2 o; o.x = pack2(v.x, v.y); o.y = pack2(v.z, v.w);
    ((uint2*)hidc)[i] = o;
    return;
  }
  b -= 16384;
  if (b < 768) {  // W_hh (1024x3072) -> WgruT cols 512..; col>=2048 remaps +1024
    packT_body(W_hh, 3072, 0, WgruT, 1536, 0, 512, 2048, 1024, 1.f, b % 48, b / 48, tile, t);
    return;
  }
  b -= 768;
  if (b < 384) {  // W_ih rows 0..511 -> WgruT cols 0..511
    packT_body(W_ih, 3072, 0, WgruT, 1536, 0, 0, 1 << 30, 0, 1.f, b % 48, b / 48, tile, t);
    return;
  }
  b -= 384;
  if (b < 32) { packT_body(Wa1, 128, 512, W1catT, 1024, 0, 0, 1 << 30, 0, 1.f, b % 2, b / 2, tile, t); return; }
  b -= 32;
  if (b < 32) { packT_body(Wg1, 128, 512, W1catT, 1024, 128, 0, 1 << 30, 0, 1.f, b % 2, b / 2, tile, t); return; }
  b -= 32;
  if (b < 16) { packT_body(Wa2, 512, 0, W2catT, 256, 0, 0, 1 << 30, 0, 1.f, b % 8, b / 8, tile, t); return; }
  b -= 16;
  if (b < 16) { packT_body(Wg2, 512, 0, W2catT, 256, 0, 128, 1 << 30, 0, -1.f, b % 8, b / 8, tile, t); return; }
  b -= 16;
  if (b < 8) {  // bias1, k-split over 8 blocks, atomic into zeroed buf
    const float* W = (t < 128) ? Wa1 : Wg1;
    int cc = t & 127;
    float acc = 0.f;
    int k0 = b * 64;
    for (int k = k0; k < k0 + 64; ++k) acc += x[k] * W[(size_t)k * 128 + cc];
    if (b == 0) acc += (t < 128) ? ba1[cc] : bg1[cc];
    atomicAdd(&bias1[t], acc);
    return;
  }
  b -= 8;
  if (b < 2) { int n = b * 256 + t; bias2[n] = ba2[n] - bg2[n]; return; }
  b -= 2;
  {
    int i = b * 256 + t;
    int p = positions[i], f = i >> 11;
    if (p > 0) atomicAdd(&counts[f * 2], 1);
    else if (p < 0) atomicAdd(&counts[f * 2 + 1], 1);
  }
}

// =====================================================================
// bf16 MFMA GEMM, 128x128, BK=32, XOR-swizzled LDS (slot = q ^ ((row>>1)&3)).
// R5: triple-buffered, depth-2 prefetch, counted vmcnt (8/4/0 tail), raw
// barriers with explicit lgkmcnt(0) release. L=4 loads/tile/wave (uniform).
// epi 1: +bias,relu ; epi 3: +bias + fused per-row sum-of-squares -> tension.
// =====================================================================
__global__ __launch_bounds__(256) void gemm_bt(
    const u16* __restrict__ A, int lda,
    const u16* __restrict__ Bt, int ldb,
    u16* __restrict__ C, int ldc,
    const float* __restrict__ bias, int epi, int K,
    float* __restrict__ tension) {
  __shared__ __align__(16) u16 As[3][128 * 32];
  __shared__ __align__(16) u16 Bs[3][128 * 32];
  const int tid = threadIdx.x;
  const int m0 = blockIdx.x * 128;
  const int n0 = blockIdx.y * 128;
  f32x4 acc[4][4] = {};
  const int lane = tid & 63;
  const int w = tid >> 6;
  const int mw = (w & 1) * 64, nw = (w >> 1) * 64;
  const int fr = lane & 15;
  const int q = lane >> 4;
  const int ar0 = tid >> 2;                     // rows 0..63 (chunk tid), +64 for chunk tid+256
  const int ag = ((tid & 3) ^ ((ar0 >> 1) & 3)) * 8;  // (row+64)>>1 keeps same &3 -> ag reused

  const u16* aB0 = A + (size_t)(m0 + ar0) * lda + ag;
  const u16* aB1 = A + (size_t)(m0 + ar0 + 64) * lda + ag;
  const u16* bB0 = Bt + (size_t)(n0 + ar0) * ldb + ag;
  const u16* bB1 = Bt + (size_t)(n0 + ar0 + 64) * ldb + ag;

  auto stage = [&](int kk, int buf) {
    __builtin_amdgcn_global_load_lds(AS1(aB0 + kk), AS3(&As[buf][tid * 8]), 16, 0, 0);
    __builtin_amdgcn_global_load_lds(AS1(aB1 + kk), AS3(&As[buf][(tid + 256) * 8]), 16, 0, 0);
    __builtin_amdgcn_global_load_lds(AS1(bB0 + kk), AS3(&Bs[buf][tid * 8]), 16, 0, 0);
    __builtin_amdgcn_global_load_lds(AS1(bB1 + kk), AS3(&Bs[buf][(tid + 256) * 8]), 16, 0, 0);
  };

  const int NT = K >> 5;   // >= 8 for all calls
  stage(0, 0);
  stage(32, 1);
  int cur = 0, nxt = 1, nx2 = 2;
#pragma unroll 1
  for (int t = 0; t < NT; ++t) {
    if (t + 2 < NT) stage((t + 2) * 32, nx2);
    const int rem = NT - 1 - t;  // tiles newer than t in flight
    if (rem >= 2)      asm volatile("s_waitcnt vmcnt(8)" ::: "memory");
    else if (rem == 1) asm volatile("s_waitcnt vmcnt(4)" ::: "memory");
    else               asm volatile("s_waitcnt vmcnt(0)" ::: "memory");
    __builtin_amdgcn_s_barrier();          // tile t fully in LDS (all waves)
    asm volatile("" ::: "memory");
    bf16x8 af[4], bfv[4];
#pragma unroll
    for (int mt = 0; mt < 4; ++mt) {
      int r = mw + mt * 16 + fr;
      af[mt] = *reinterpret_cast<const bf16x8*>(&As[cur][r * 32 + ((q ^ ((r >> 1) & 3)) * 8)]);
    }
#pragma unroll
    for (int nt = 0; nt < 4; ++nt) {
      int r = nw + nt * 16 + fr;
      bfv[nt] = *reinterpret_cast<const bf16x8*>(&Bs[cur][r * 32 + ((q ^ ((r >> 1) & 3)) * 8)]);
    }
    __builtin_amdgcn_s_setprio(1);
#pragma unroll
    for (int mt = 0; mt < 4; ++mt)
#pragma unroll
      for (int nt = 0; nt < 4; ++nt)
        acc[mt][nt] = __builtin_amdgcn_mfma_f32_16x16x32_bf16(af[mt], bfv[nt], acc[mt][nt], 0, 0, 0);
    __builtin_amdgcn_s_setprio(0);
    asm volatile("s_waitcnt lgkmcnt(0)" ::: "memory");  // my ds_reads retired
    __builtin_amdgcn_s_barrier();          // buf[cur] safe to overwrite at t+1
    int tmp = cur; cur = nxt; nxt = nx2; nx2 = tmp;
  }
  const int rq = q * 4;  // D: col=lane&15, row=rq+reg [m89]
#pragma unroll
  for (int mt = 0; mt < 4; ++mt) {
    float srow[4] = {0.f, 0.f, 0.f, 0.f};
#pragma unroll
    for (int nt = 0; nt < 4; ++nt) {
      int col = n0 + nw + nt * 16 + fr;
      f32x4 v = acc[mt][nt];
#pragma unroll
      for (int r = 0; r < 4; ++r) {
        int row = m0 + mw + mt * 16 + rq + r;
        float val = v[r] + bias[col];
        if (epi == 1) val = val > 0.f ? val : 0.f;
        else srow[r] += val * val;
        C[(size_t)row * ldc + col] = f2bf(val);
      }
    }
    if (epi == 3) {
#pragma unroll
      for (int r = 0; r < 4; ++r) {
        float s = srow[r];
        s += __shfl_xor(s, 1, 16); s += __shfl_xor(s, 2, 16);
        s += __shfl_xor(s, 4, 16); s += __shfl_xor(s, 8, 16);
        if (fr == 0) atomicAdd(&tension[m0 + mw + mt * 16 + rq + r], s);
      }
    }
  }
}

// =====================================================================
// Fused GRU GEMM+gates. 512 threads / 8 waves, 128 rows x 64 hid-cols,
// 4 regions (r,z,gi_n,gh_n), acc 64 regs/thread. R5: merged 48-step K-stream
// (WgruT k-off == s*32 across both phases), triple-buffered LDS (60KB),
// depth-2 prefetch, counted vmcnt (bsel0 waves L=3 -> 6/3/0; bsel1 L=2 ->
// 4/2/0). Loop split at t=16 keeps the gated-region acc index compile-time.
// =====================================================================
__global__ __launch_bounds__(512, 4) void gemm_gru(
    const u16* __restrict__ outbf, const u16* __restrict__ hidc,
    const u16* __restrict__ WgruT,
    const float* __restrict__ W_ihf, const float* __restrict__ bihf,
    const float* __restrict__ bhhf, const float* __restrict__ wealthf,
    const float* __restrict__ tension, u16* __restrict__ hpre) {
  __shared__ __align__(16) u16 As[3][128 * 32];
  __shared__ __align__(16) u16 Bs[3][3][64 * 32];
  const int tid = threadIdx.x;
  const int m0 = blockIdx.x * 128;
  const int j0 = blockIdx.y * 64;
  f32x4 acc[4][2][2] = {};  // [region][mt][nt]
  const int lane = tid & 63;
  const int w = tid >> 6;
  const int mw = (w & 3) * 32, nw = (w >> 2) * 32;
  const int fr = lane & 15;
  const int q = lane >> 4;
  // A staging: 512 chunks (128 rows x 4 slots), chunk = tid
  const int arow = tid >> 2;
  const int ag = ((tid & 3) ^ ((arow >> 1) & 3)) * 8;
  // B staging: 256 chunks/region (64 rows x 4 slots)
  const int ct = tid & 255;
  const int brow = ct >> 2;
  const int bg = ((ct & 3) ^ ((brow >> 1) & 3)) * 8;
  const int bsel = tid >> 8;  // wave-uniform

  // per-thread base addresses (loop-invariant)
  const u16* aB0 = outbf + (size_t)(m0 + arow) * 512 + ag;   // phase 0, lda=512
  const u16* aB1 = hidc + (size_t)(m0 + arow) * 1024 + ag;   // phase 1, lda=1024
  // bsel0 waves: bBR = region r rows; region-2/3 = bBR + 2048*1536 (+1024*1536 ph1)
  // bsel1 waves: bBR = region z rows (+1024)
  const u16* bBR = WgruT + (size_t)((bsel ? 1024 : 0) + j0 + brow) * 1536 + bg;

  auto stage = [&](int s, int buf) {  // s = global K-step 0..47
    const int p = s >= 16;
    const u16* ap = p ? (aB1 + (s - 16) * 32) : (aB0 + s * 32);
    __builtin_amdgcn_global_load_lds(AS1(ap), AS3(&As[buf][tid * 8]), 16, 0, 0);
    const int kk = s * 32;  // == WgruT k offset in both phases
    if (bsel == 0) {
      __builtin_amdgcn_global_load_lds(AS1(bBR + kk), AS3(&Bs[buf][0][ct * 8]), 16, 0, 0);
      __builtin_amdgcn_global_load_lds(
          AS1(bBR + (size_t)(2048 * 1536 + (p ? 1024 * 1536 : 0) + kk)),
          AS3(&Bs[buf][2][ct * 8]), 16, 0, 0);
    } else {
      __builtin_amdgcn_global_load_lds(AS1(bBR + kk), AS3(&Bs[buf][1][ct * 8]), 16, 0, 0);
    }
  };

  stage(0, 0);
  stage(1, 1);
  int cur = 0, nxt = 1, nx2 = 2;

#define GRU_STEP(T, REG3)                                                                     \
  {                                                                                           \
    if ((T) < 46) {                                                                           \
      stage((T) + 2, nx2);                                                                    \
      if (bsel == 0) asm volatile("s_waitcnt vmcnt(6)" ::: "memory");                         \
      else           asm volatile("s_waitcnt vmcnt(4)" ::: "memory");                         \
    } else if ((T) == 46) {                                                                   \
      if (bsel == 0) asm volatile("s_waitcnt vmcnt(3)" ::: "memory");                         \
      else           asm volatile("s_waitcnt vmcnt(2)" ::: "memory");                         \
    } else {                                                                                  \
      asm volatile("s_waitcnt vmcnt(0)" ::: "memory");                                        \
    }                                                                                         \
    __builtin_amdgcn_s_barrier();                                                             \
    asm volatile("" ::: "memory");                                                            \
    bf16x8 af[2], b0v[2], b1v[2], b2v[2];                                                     \
    _Pragma("unroll")                                                                         \
    for (int mt = 0; mt < 2; ++mt) {                                                          \
      int r = mw + mt * 16 + fr;                                                              \
      af[mt] = *reinterpret_cast<const bf16x8*>(&As[cur][r * 32 + ((q ^ ((r >> 1) & 3)) * 8)]);\
    }                                                                                         \
    _Pragma("unroll")                                                                         \
    for (int nt = 0; nt < 2; ++nt) {                                                          \
      int r = nw + nt * 16 + fr;                                                              \
      int ss = (q ^ ((r >> 1) & 3)) * 8;                                                      \
      b0v[nt] = *reinterpret_cast<const bf16x8*>(&Bs[cur][0][r * 32 + ss]);                   \
      b1v[nt] = *reinterpret_cast<const bf16x8*>(&Bs[cur][1][r * 32 + ss]);                   \
      b2v[nt] = *reinterpret_cast<const bf16x8*>(&Bs[cur][2][r * 32 + ss]);                   \
    }                                                                                         \
    __builtin_amdgcn_s_setprio(1);                                                            \
    _Pragma("unroll")                                                                         \
    for (int mt = 0; mt < 2; ++mt)                                                            \
      _Pragma("unroll")                                                                       \
      for (int nt = 0; nt < 2; ++nt) {                                                        \
        acc[0][mt][nt] = __builtin_amdgcn_mfma_f32_16x16x32_bf16(af[mt], b0v[nt], acc[0][mt][nt], 0, 0, 0); \
        acc[1][mt][nt] = __builtin_amdgcn_mfma_f32_16x16x32_bf16(af[mt], b1v[nt], acc[1][mt][nt], 0, 0, 0); \
        acc[REG3][mt][nt] = __builtin_amdgcn_mfma_f32_16x16x32_bf16(af[mt], b2v[nt], acc[REG3][mt][nt], 0, 0, 0); \
      }                                                                                       \
    __builtin_amdgcn_s_setprio(0);                                                            \
    asm volatile("s_waitcnt lgkmcnt(0)" ::: "memory");                                        \
    __builtin_amdgcn_s_barrier();                                                             \
    int tmp = cur; cur = nxt; nxt = nx2; nx2 = tmp;                                           \
  }

#pragma unroll 1
  for (int t = 0; t < 16; ++t) GRU_STEP(t, 2)   // phase 0: gi_n
#pragma unroll 1
  for (int t = 16; t < 48; ++t) GRU_STEP(t, 3)  // phase 1: gh_n
#undef GRU_STEP

  // epilogue: D col=lane&15, row=(lane>>4)*4+reg [m89]
  const int rq = q * 4;
  const float* wt = W_ihf + (size_t)512 * 3072;  // tension row
  float wtr[2], wtz[2], wtn[2], bir[2], biz[2], bin_[2], bhr_[2], bhz_[2], bhn_[2];
#pragma unroll
  for (int nt = 0; nt < 2; ++nt) {
    int j = j0 + nw + nt * 16 + fr;
    wtr[nt] = wt[j]; wtz[nt] = wt[1024 + j]; wtn[nt] = wt[2048 + j];
    bir[nt] = bihf[j]; biz[nt] = bihf[1024 + j]; bin_[nt] = bihf[2048 + j];
    bhr_[nt] = bhhf[j]; bhz_[nt] = bhhf[1024 + j]; bhn_[nt] = bhhf[2048 + j];
  }
#pragma unroll
  for (int mt = 0; mt < 2; ++mt) {
#pragma unroll
    for (int rr = 0; rr < 4; ++rr) {
      int row = m0 + mw + mt * 16 + rq + rr;
      float tv = tension[row] * (1.f / 512.f);
      float wl = fminf(fmaxf(wealthf[row], 0.1f), 2.0f);
      float mod = 0.9f + 0.1f * wl;
#pragma unroll
      for (int nt = 0; nt < 2; ++nt) {
        int j = j0 + nw + nt * 16 + fr;
        float r = sigm(acc[0][mt][nt][rr] + tv * wtr[nt] + bir[nt] + bhr_[nt]);
        float z = sigm(acc[1][mt][nt][rr] + tv * wtz[nt] + biz[nt] + bhz_[nt]);
        float n = fast_tanh(acc[2][mt][nt][rr] + tv * wtn[nt] + bin_[nt]
                            + r * (acc[3][mt][nt][rr] + bhn_[nt]));
        float h = bf2f(hidc[(size_t)row * 1024 + j]);
        float h2 = (1.f - z) * n + z * h;
        h2 = fminf(fmaxf(h2 * mod, -10.f), 10.f);
        hpre[(size_t)row * 1024 + j] = f2bf(h2);
      }
    }
  }
}

// =====================================================================
__global__ void stats_kernel(const u16* __restrict__ hpre, const int* __restrict__ positions,
                             float* __restrict__ fsums) {
  int cc = blockIdx.x, f = blockIdx.y, z = blockIdx.z, t = threadIdx.x;
  int col = cc * 128 + (t & 127);
  int half = t >> 7;
  float st = 0, sp = 0, sm = 0;
  for (int it = 0; it < 128; ++it) {
    int row = (f << 11) + ((z * 128 + it) << 1) + half;
    int p = positions[row];
    float v = bf2f(hpre[(size_t)row * 1024 + col]);
    st += v;
    if (p > 0) sp += v;
    if (p < 0) sm += v;
  }
  atomicAdd(&fsums[(f * 3 + 0) * 1024 + col], st);
  atomicAdd(&fsums[(f * 3 + 1) * 1024 + col], sp);
  atomicAdd(&fsums[(f * 3 + 2) * 1024 + col], sm);
}

__global__ void derive_kernel(const float* __restrict__ fsums, const int* __restrict__ counts,
                              float* __restrict__ mean1, float* __restrict__ mean2,
                              float* __restrict__ fmean, float* __restrict__ gop,
                              float* __restrict__ scal) {
  int c = threadIdx.x;  // 1024
  int cnt1 = 0, cnt2 = 0, cf1[8], cf2[8];
#pragma unroll
  for (int f = 0; f < 8; ++f) {
    cf1[f] = counts[f * 2]; cf2[f] = counts[f * 2 + 1];
    cnt1 += cf1[f]; cnt2 += cf2[f];
  }
  float s1 = 0, s2 = 0;
#pragma unroll
  for (int f = 0; f < 8; ++f) { s1 += fsums[(f * 3 + 1) * 1024 + c]; s2 += fsums[(f * 3 + 2) * 1024 + c]; }
  float m1 = s1 / (float)(cnt1 > 1 ? cnt1 : 1);
  float m2 = s2 / (float)(cnt2 > 1 ? cnt2 : 1);
  float a1 = (cnt1 >= 2) ? 0.1f : 0.f;
  float a2 = (cnt2 >= 2) ? 0.1f : 0.f;
  float g = 0;
#pragma unroll
  for (int f = 0; f < 8; ++f) {
    float fm = (fsums[(f * 3) * 1024 + c]
                + a1 * ((float)cf1[f] * m1 - fsums[(f * 3 + 1) * 1024 + c])
                + a2 * ((float)cf2[f] * m2 - fsums[(f * 3 + 2) * 1024 + c])) * (1.f / 2048.f);
    fmean[f * 1024 + c] = fm;
    g += fm;
  }
  gop[c] = g * 0.125f;
  mean1[c] = m1; mean2[c] = m2;
  if (c == 0) { scal[0] = a1; scal[1] = a2; }
}

__global__ void finalize_kernel(const u16* __restrict__ hpre, const int* __restrict__ positions,
                                const int* __restrict__ step, const float* __restrict__ mean1,
                                const float* __restrict__ mean2, const float* __restrict__ fmean,
                                const float* __restrict__ gop, const float* __restrict__ scal,
                                float* __restrict__ out) {
  int row = blockIdx.x, t = threadIdx.x;
  int p = positions[row];
  float w1 = (p > 0) ? scal[0] : 0.f;
  float w2 = (p < 0) ? scal[1] : 0.f;
  int f = row >> 11, q = row & 2047;
  bool deb = (step[0] > 5) && (q < 512);
  const u16* hrow = hpre + (size_t)row * 1024;
  const float* fmp = fmean + f * 1024;
  float* orow = out + 513 + (size_t)row * 1024;
#pragma unroll
  for (int e = 0; e < 8; ++e) {
    int c = e * 128 + t;
    float h = bf2f(hrow[c]);
    float hgs = h + w1 * (mean1[c] - h) + w2 * (mean2[c] - h);
    float hfs = 0.85f * hgs + 0.15f * fmp[c];
    orow[c] = deb ? (0.85f * hfs + 0.15f * gop[c]) : hfs;
  }
}

__global__ void softmax_kernel(const float* __restrict__ tension, float* __restrict__ weights,
                               float* __restrict__ out) {
  __shared__ float red[1024];
  int t = threadIdx.x;
  float tv[16], mx = -1e30f, sumt = 0.f;
#pragma unroll
  for (int k = 0; k < 16; ++k) {
    tv[k] = tension[t + k * 1024] * (1.f / 512.f);
    mx = fmaxf(mx, tv[k]); sumt += tv[k];
  }
  red[t] = mx; __syncthreads();
  for (int s = 512; s > 0; s >>= 1) { if (t < s) red[t] = fmaxf(red[t], red[t + s]); __syncthreads(); }
  float m = red[0]; __syncthreads();
  red[t] = sumt; __syncthreads();
  for (int s = 512; s > 0; s >>= 1) { if (t < s) red[t] += red[t + s]; __syncthreads(); }
  float tot = red[0]; __syncthreads();
  float ev[16], se = 0.f;
#pragma unroll
  for (int k = 0; k < 16; ++k) { ev[k] = __expf(tv[k] - m); se += ev[k]; }
  red[t] = se; __syncthreads();
  for (int s = 512; s > 0; s >>= 1) { if (t < s) red[t] += red[t + s]; __syncthreads(); }
  float invS = 1.f / red[0];
#pragma unroll
  for (int k = 0; k < 16; ++k) weights[t + k * 1024] = ev[k] * invS;
  if (t == 0) out[512] = tot * (1.f / 16384.f);
}

__global__ void wsum_kernel(const float* __restrict__ weights, const u16* __restrict__ outbf,
                            float* __restrict__ co) {
  int b = blockIdx.x, t = threadIdx.x;
  int c = t * 2;
  float a0 = 0.f, a1 = 0.f;
  int i0 = b * 128;
  for (int i = i0; i < i0 + 128; ++i) {
    float w = weights[i];
    unsigned v = *reinterpret_cast<const unsigned*>(outbf + (size_t)i * 512 + c);
    a0 += w * bf2f(v & 0xffff);
    a1 += w * bf2f(v >> 16);
  }
  atomicAdd(&co[c], a0);
  atomicAdd(&co[c + 1], a1);
}

__global__ void pred_kernel(const float* __restrict__ co, const float* __restrict__ Wof,
                            const float* __restrict__ bof, float* __restrict__ out) {
  __shared__ float cs[512];
  int t = threadIdx.x, n = blockIdx.x * 256 + t;
  cs[t] = co[t]; cs[t + 256] = co[t + 256];
  __syncthreads();
  float acc = bof[n];
  for (int ck = 0; ck < 512; ++ck) acc += cs[ck] * Wof[(size_t)ck * 512 + n];
  out[n] = acc;
}

// =====================================================================
extern "C" void kernel_launch(void* const* d_in, const int* in_sizes, int n_in,
                              void* d_out, int out_size, void* d_ws, size_t ws_size,
                              hipStream_t stream) {
  const float* x      = (const float*)d_in[0];
  const float* hid    = (const float*)d_in[1];
  const float* wealth = (const float*)d_in[2];
  const float* Wa1    = (const float*)d_in[3];
  const float* ba1    = (const float*)d_in[4];
  const float* Wa2    = (const float*)d_in[5];
  const float* ba2    = (const float*)d_in[6];
  const float* Wg1    = (const float*)d_in[7];
  const float* bg1    = (const float*)d_in[8];
  const float* Wg2    = (const float*)d_in[9];
  const float* bg2    = (const float*)d_in[10];
  const float* W_ih   = (const float*)d_in[11];
  const float* W_hh   = (const float*)d_in[12];
  const float* b_ih   = (const float*)d_in[13];
  const float* b_hh   = (const float*)d_in[14];
  const float* Wo     = (const float*)d_in[15];
  const float* bo     = (const float*)d_in[16];
  const int* positions= (const int*)d_in[17];
  const int* step     = (const int*)d_in[18];
  float* out = (float*)d_out;  // [0,512) pred | [512] avg_tension | [513..) new_h

  char* w = (char*)d_ws;
  size_t off = 0;
  auto alloc = [&](size_t bytes) { void* p = w + off; off += (bytes + 255) & ~(size_t)255; return p; };
  u16*   hidc    = (u16*)  alloc((size_t)NC * 1024 * 2);
  u16*   outbf   = (u16*)  alloc((size_t)NC * 512 * 2);
  u16*   hpre    = (u16*)  alloc((size_t)NC * 1024 * 2);
  u16*   WgruT   = (u16*)  alloc((size_t)4096 * 1536 * 2);
  u16*   W1catT  = (u16*)  alloc((size_t)256 * 1024 * 2);
  u16*   W2catT  = (u16*)  alloc((size_t)512 * 256 * 2);
  u16*   t1      = (u16*)  alloc((size_t)NC * 256 * 2);
  // zeroed contiguous: bias1 | co | counts | fsums | tension
  float* bias1   = (float*)alloc(256 * 4);
  float* co      = (float*)alloc(512 * 4);
  int*   counts  = (int*)  alloc(16 * 4);
  float* fsums   = (float*)alloc(8 * 3 * 1024 * 4);
  float* tension = (float*)alloc(NC * 4);
  float* bias2   = (float*)alloc(512 * 4);
  float* weights = (float*)alloc(NC * 4);
  float* mean1   = (float*)alloc(1024 * 4);
  float* mean2   = (float*)alloc(1024 * 4);
  float* gop     = (float*)alloc(1024 * 4);
  float* fmean   = (float*)alloc(8 * 1024 * 4);
  float* scal    = (float*)alloc(8 * 4);

  hipMemsetAsync(bias1, 0, 1024 + 2048 + 256 + 98304 + 65536, stream);

  // cvt (16384) + packT (1248) + smalls (74)
  prep_kernel<<<17706, 256, 0, stream>>>(hid, hidc, W_ih, W_hh, WgruT,
                                         Wa1, Wg1, W1catT, Wa2, Wg2, W2catT,
                                         x, ba1, bg1, bias1, ba2, bg2, bias2,
                                         positions, counts);

  // t1 = relu(h @ W1 + bias1)   M=16384 K=1024 N=256
  gemm_bt<<<dim3(128, 2), 256, 0, stream>>>(hidc, 1024, W1catT, 1024, t1, 256,
                                            bias1, 1, 1024, nullptr);
  // output = t1 @ [Wa2;-Wg2] + (ba2-bg2); fused tension
  gemm_bt<<<dim3(128, 4), 256, 0, stream>>>(t1, 256, W2catT, 256, outbf, 512,
                                            bias2, 3, 256, tension);

  // fused GRU (128x64 tiles, 2048 blocks, 512 threads)
  gemm_gru<<<dim3(128, 16), 512, 0, stream>>>(outbf, hidc, WgruT, W_ih, b_ih, b_hh,
                                              wealth, tension, hpre);

  stats_kernel<<<dim3(8, 8, 8), 256, 0, stream>>>(hpre, positions, fsums);
  derive_kernel<<<1, 1024, 0, stream>>>(fsums, counts, mean1, mean2, fmean, gop, scal);
  finalize_kernel<<<NC, 128, 0, stream>>>(hpre, positions, step, mean1, mean2, fmean, gop,
                                          scal, out);

  softmax_kernel<<<1, 1024, 0, stream>>>(tension, weights, out);
  wsum_kernel<<<128, 256, 0, stream>>>(weights, outbf, co);
  pred_kernel<<<2, 256, 0, stream>>>(co, Wo, bo, out);

  (void)in_sizes; (void)n_in; (void)out_size; (void)ws_size;
}

// Round 2
// 577.510 us; speedup vs baseline: 1.0436x; 1.0369x over previous
//
#include <hip/hip_runtime.h>
#include <stdint.h>

typedef unsigned short u16;
typedef __bf16 bf16x8 __attribute__((ext_vector_type(8)));
typedef float f32x4 __attribute__((ext_vector_type(4)));

// f32 inputs/outputs (verified R2). GEMMs run bf16 MFMA (absmax 0.0156 << 0.05).
// R4: (1) compile-time acc idx, (2) swizzled LDS, (3) occupancy cliffs at 64/128/256 VGPR.
// R5: counted-vmcnt graft on 2-barrier loop = null (regime gate: T4 needs phase structure).
// R6: gemm_gru redesigned m201-style: BM=128 x BJ=128 x 4reg, BK=64, 8 waves of
// 64x32x4reg (acc=128 VGPR), dbuf LDS 128KB, per-K-tile {ds ks0 | 24 MFMA | ds ks1 |
// lgkm0+bar | stage t+2 | 24 MFMA | vmcnt(8)+bar}. reads/MFMA 0.67 -> 0.42.

__device__ __forceinline__ float bf2f(unsigned u) { return __uint_as_float(u << 16); }
__device__ __forceinline__ u16 f2bf(float f) {
  unsigned x = __float_as_uint(f);
  unsigned r = x + 0x7fffu + ((x >> 16) & 1u);
  return (u16)(r >> 16);
}
__device__ __forceinline__ unsigned pack2(float a, float b) {
  return (unsigned)f2bf(a) | ((unsigned)f2bf(b) << 16);
}
__device__ __forceinline__ float sigm(float x) { return 1.f / (1.f + __expf(-x)); }
__device__ __forceinline__ float fast_tanh(float x) {
  float e = __expf(2.f * x);
  return 1.f - 2.f / (e + 1.f);
}

#define AS1(p) ((const __attribute__((address_space(1))) void*)(p))
#define AS3(p) ((__attribute__((address_space(3))) void*)(p))

#define NC 16384

// =====================================================================
// prep: [0,16384) hid f32->bf16 cvt ; [16384,17632) weight transposes ;
// [17632,17706) smalls (bias1/bias2/counts). One launch.
// =====================================================================
__device__ __forceinline__ void packT_body(
    const float* __restrict__ src, int sld, int srow0,
    u16* __restrict__ dst, int dld, int drow0, int koff,
    int remapThresh, int remapAdd, float sgn, int bx, int by,
    float (*tile)[65], int t) {
  const int k0 = by * 64, c0 = bx * 64;
  const int tx = t & 15, ty = t >> 4;
#pragma unroll
  for (int p = 0; p < 4; ++p) {
    int r = ty + p * 16;
    float4 v = *reinterpret_cast<const float4*>(&src[(size_t)(srow0 + k0 + r) * sld + c0 + tx * 4]);
    tile[tx * 4 + 0][r] = v.x;
    tile[tx * 4 + 1][r] = v.y;
    tile[tx * 4 + 2][r] = v.z;
    tile[tx * 4 + 3][r] = v.w;
  }
  __syncthreads();
  const int cl = t >> 2;
  const int kb = (t & 3) * 16;
  int col = c0 + cl;
  int row = drow0 + col + ((col >= remapThresh) ? remapAdd : 0);
  union { u16 o[16]; uint4 v[2]; } u;
#pragma unroll
  for (int e = 0; e < 16; ++e) u.o[e] = f2bf(sgn * tile[cl][kb + e]);
  uint4* d = reinterpret_cast<uint4*>(&dst[(size_t)row * dld + koff + k0 + kb]);
  d[0] = u.v[0]; d[1] = u.v[1];
}

__global__ __launch_bounds__(256) void prep_kernel(
    const float* __restrict__ hid, u16* __restrict__ hidc,
    const float* __restrict__ W_ih, const float* __restrict__ W_hh, u16* __restrict__ WgruT,
    const float* __restrict__ Wa1, const float* __restrict__ Wg1, u16* __restrict__ W1catT,
    const float* __restrict__ Wa2, const float* __restrict__ Wg2, u16* __restrict__ W2catT,
    const float* __restrict__ x, const float* __restrict__ ba1, const float* __restrict__ bg1,
    float* __restrict__ bias1, const float* __restrict__ ba2, const float* __restrict__ bg2,
    float* __restrict__ bias2, const int* __restrict__ positions, int* __restrict__ counts) {
  __shared__ float tile[64][65];
  int b = blockIdx.x, t = threadIdx.x;
  if (b < 16384) {  // cvt: 4 f32 -> 4 bf16 per thread, fully coalesced
    int i = b * 256 + t;
    float4 v = ((const float4*)hid)[i];
    uint2 o; o.x = pack2(v.x, v.y); o.y = pack2(v.z, v.w);
    ((uint2*)hidc)[i] = o;
    return;
  }
  b -= 16384;
  if (b < 768) {  // W_hh (1024x3072) -> WgruT cols 512..; col>=2048 remaps +1024
    packT_body(W_hh, 3072, 0, WgruT, 1536, 0, 512, 2048, 1024, 1.f, b % 48, b / 48, tile, t);
    return;
  }
  b -= 768;
  if (b < 384) {  // W_ih rows 0..511 -> WgruT cols 0..511
    packT_body(W_ih, 3072, 0, WgruT, 1536, 0, 0, 1 << 30, 0, 1.f, b % 48, b / 48, tile, t);
    return;
  }
  b -= 384;
  if (b < 32) { packT_body(Wa1, 128, 512, W1catT, 1024, 0, 0, 1 << 30, 0, 1.f, b % 2, b / 2, tile, t); return; }
  b -= 32;
  if (b < 32) { packT_body(Wg1, 128, 512, W1catT, 1024, 128, 0, 1 << 30, 0, 1.f, b % 2, b / 2, tile, t); return; }
  b -= 32;
  if (b < 16) { packT_body(Wa2, 512, 0, W2catT, 256, 0, 0, 1 << 30, 0, 1.f, b % 8, b / 8, tile, t); return; }
  b -= 16;
  if (b < 16) { packT_body(Wg2, 512, 0, W2catT, 256, 0, 128, 1 << 30, 0, -1.f, b % 8, b / 8, tile, t); return; }
  b -= 16;
  if (b < 8) {  // bias1, k-split over 8 blocks, atomic into zeroed buf
    const float* W = (t < 128) ? Wa1 : Wg1;
    int cc = t & 127;
    float acc = 0.f;
    int k0 = b * 64;
    for (int k = k0; k < k0 + 64; ++k) acc += x[k] * W[(size_t)k * 128 + cc];
    if (b == 0) acc += (t < 128) ? ba1[cc] : bg1[cc];
    atomicAdd(&bias1[t], acc);
    return;
  }
  b -= 8;
  if (b < 2) { int n = b * 256 + t; bias2[n] = ba2[n] - bg2[n]; return; }
  b -= 2;
  {
    int i = b * 256 + t;
    int p = positions[i], f = i >> 11;
    if (p > 0) atomicAdd(&counts[f * 2], 1);
    else if (p < 0) atomicAdd(&counts[f * 2 + 1], 1);
  }
}

// =====================================================================
// bf16 MFMA GEMM, 128x128, BK=32, XOR-swizzled LDS (slot = q ^ ((row>>1)&3)).
// Triple-buffered, depth-2 prefetch, counted vmcnt. epi 1: +bias,relu ;
// epi 3: +bias + fused per-row sum-of-squares -> tension.
// =====================================================================
__global__ __launch_bounds__(256) void gemm_bt(
    const u16* __restrict__ A, int lda,
    const u16* __restrict__ Bt, int ldb,
    u16* __restrict__ C, int ldc,
    const float* __restrict__ bias, int epi, int K,
    float* __restrict__ tension) {
  __shared__ __align__(16) u16 As[3][128 * 32];
  __shared__ __align__(16) u16 Bs[3][128 * 32];
  const int tid = threadIdx.x;
  const int m0 = blockIdx.x * 128;
  const int n0 = blockIdx.y * 128;
  f32x4 acc[4][4] = {};
  const int lane = tid & 63;
  const int w = tid >> 6;
  const int mw = (w & 1) * 64, nw = (w >> 1) * 64;
  const int fr = lane & 15;
  const int q = lane >> 4;
  const int ar0 = tid >> 2;                     // rows 0..63 (chunk tid), +64 for chunk tid+256
  const int ag = ((tid & 3) ^ ((ar0 >> 1) & 3)) * 8;  // (row+64)>>1 keeps same &3 -> ag reused

  const u16* aB0 = A + (size_t)(m0 + ar0) * lda + ag;
  const u16* aB1 = A + (size_t)(m0 + ar0 + 64) * lda + ag;
  const u16* bB0 = Bt + (size_t)(n0 + ar0) * ldb + ag;
  const u16* bB1 = Bt + (size_t)(n0 + ar0 + 64) * ldb + ag;

  auto stage = [&](int kk, int buf) {
    __builtin_amdgcn_global_load_lds(AS1(aB0 + kk), AS3(&As[buf][tid * 8]), 16, 0, 0);
    __builtin_amdgcn_global_load_lds(AS1(aB1 + kk), AS3(&As[buf][(tid + 256) * 8]), 16, 0, 0);
    __builtin_amdgcn_global_load_lds(AS1(bB0 + kk), AS3(&Bs[buf][tid * 8]), 16, 0, 0);
    __builtin_amdgcn_global_load_lds(AS1(bB1 + kk), AS3(&Bs[buf][(tid + 256) * 8]), 16, 0, 0);
  };

  const int NT = K >> 5;   // >= 8 for all calls
  stage(0, 0);
  stage(32, 1);
  int cur = 0, nxt = 1, nx2 = 2;
#pragma unroll 1
  for (int t = 0; t < NT; ++t) {
    if (t + 2 < NT) stage((t + 2) * 32, nx2);
    const int rem = NT - 1 - t;  // tiles newer than t in flight
    if (rem >= 2)      asm volatile("s_waitcnt vmcnt(8)" ::: "memory");
    else if (rem == 1) asm volatile("s_waitcnt vmcnt(4)" ::: "memory");
    else               asm volatile("s_waitcnt vmcnt(0)" ::: "memory");
    __builtin_amdgcn_s_barrier();          // tile t fully in LDS (all waves)
    asm volatile("" ::: "memory");
    bf16x8 af[4], bfv[4];
#pragma unroll
    for (int mt = 0; mt < 4; ++mt) {
      int r = mw + mt * 16 + fr;
      af[mt] = *reinterpret_cast<const bf16x8*>(&As[cur][r * 32 + ((q ^ ((r >> 1) & 3)) * 8)]);
    }
#pragma unroll
    for (int nt = 0; nt < 4; ++nt) {
      int r = nw + nt * 16 + fr;
      bfv[nt] = *reinterpret_cast<const bf16x8*>(&Bs[cur][r * 32 + ((q ^ ((r >> 1) & 3)) * 8)]);
    }
    __builtin_amdgcn_s_setprio(1);
#pragma unroll
    for (int mt = 0; mt < 4; ++mt)
#pragma unroll
      for (int nt = 0; nt < 4; ++nt)
        acc[mt][nt] = __builtin_amdgcn_mfma_f32_16x16x32_bf16(af[mt], bfv[nt], acc[mt][nt], 0, 0, 0);
    __builtin_amdgcn_s_setprio(0);
    asm volatile("s_waitcnt lgkmcnt(0)" ::: "memory");  // my ds_reads retired
    __builtin_amdgcn_s_barrier();          // buf[cur] safe to overwrite at t+1
    int tmp = cur; cur = nxt; nxt = nx2; nx2 = tmp;
  }
  const int rq = q * 4;  // D: col=lane&15, row=rq+reg [m89]
#pragma unroll
  for (int mt = 0; mt < 4; ++mt) {
    float srow[4] = {0.f, 0.f, 0.f, 0.f};
#pragma unroll
    for (int nt = 0; nt < 4; ++nt) {
      int col = n0 + nw + nt * 16 + fr;
      f32x4 v = acc[mt][nt];
#pragma unroll
      for (int r = 0; r < 4; ++r) {
        int row = m0 + mw + mt * 16 + rq + r;
        float val = v[r] + bias[col];
        if (epi == 1) val = val > 0.f ? val : 0.f;
        else srow[r] += val * val;
        C[(size_t)row * ldc + col] = f2bf(val);
      }
    }
    if (epi == 3) {
#pragma unroll
      for (int r = 0; r < 4; ++r) {
        float s = srow[r];
        s += __shfl_xor(s, 1, 16); s += __shfl_xor(s, 2, 16);
        s += __shfl_xor(s, 4, 16); s += __shfl_xor(s, 8, 16);
        if (fr == 0) atomicAdd(&tension[m0 + mw + mt * 16 + rq + r], s);
      }
    }
  }
}

// =====================================================================
// R6 fused GRU. 512 threads / 8 waves; block tile 128 rows x 128 j-cols x
// 4 regions; BK=64; wave = 64 rows x 32 j x 4 reg (acc[4][4][2] = 128 VGPR).
// LDS: dbuf As[2][128][64] (32KB) + Bs[2][3][128][64] (96KB) = 128KB, 1 blk/CU.
// Layout [row][64] u16, row stride 128B: slot' = slot ^ (row&7) (pre-swizzled
// global source, rule #21; per-16-lane phase => 2-way = free).
// Per K-tile: ds ks0(10) | 24 MFMA | ds ks1(10) | lgkm0+bar | stage t+2 (8 gld)
// | 24 MFMA | vmcnt(8)+bar. Counted vmcnt in steady state (T3+T4).
// Tiles 0..7: A=outbf (K 0..511), reg3=gi_n(rows 2048+). Tiles 8..23: A=hidc,
// reg3=gh_n(rows 3072+). WgruT k index = s*64 uniformly.
// =====================================================================
__global__ __launch_bounds__(512, 2) void gemm_gru(
    const u16* __restrict__ outbf, const u16* __restrict__ hidc,
    const u16* __restrict__ WgruT,
    const float* __restrict__ W_ihf, const float* __restrict__ bihf,
    const float* __restrict__ bhhf, const float* __restrict__ wealthf,
    const float* __restrict__ tension, u16* __restrict__ hpre) {
  __shared__ __align__(16) u16 As[2][128 * 64];
  __shared__ __align__(16) u16 Bs[2][3][128 * 64];
  const int tid = threadIdx.x;
  const int m0 = blockIdx.x * 128;
  const int j0 = blockIdx.y * 128;
  f32x4 acc[4][4][2] = {};  // [region][mt][nt]
  const int lane = tid & 63;
  const int w = tid >> 6;
  const int mw = (w & 1) * 64, jw = (w >> 1) * 32;
  const int fr = lane & 15;
  const int q = lane >> 4;
  // staging: chunk = tid -> LDS (row = tid>>3, slot = tid&7); global source
  // k-group pre-swizzled: gslot = slot ^ (row&7)  (involution; +64 rows keeps &7)
  const int rowl = tid >> 3;
  const int koffT = ((tid & 7) ^ (rowl & 7)) * 8;
  const size_t aOutB = (size_t)(m0 + rowl) * 512 + koffT;
  const size_t aHidB = (size_t)(m0 + rowl) * 1024 + koffT;
  const size_t bB    = (size_t)(j0 + rowl) * 1536 + koffT;
  // frag-read slot offsets (u16): slot' = (ks*4+q)^(fr&7), *8 elems
  const int f7 = fr & 7;
  const int sk0 = (q ^ f7) * 8;
  const int sk1 = ((4 + q) ^ f7) * 8;

#define STAGE(S, BUF)                                                                              \
  {                                                                                                \
    const size_t kO = (size_t)(S) * 64;                                                            \
    if ((S) < 8) {                                                                                 \
      __builtin_amdgcn_global_load_lds(AS1(outbf + aOutB + kO), AS3(&As[BUF][tid * 8]), 16, 0, 0); \
      __builtin_amdgcn_global_load_lds(AS1(outbf + aOutB + (size_t)64 * 512 + kO),                 \
                                       AS3(&As[BUF][4096 + tid * 8]), 16, 0, 0);                   \
    } else {                                                                                       \
      const size_t kO1 = (size_t)((S) - 8) * 64;                                                   \
      __builtin_amdgcn_global_load_lds(AS1(hidc + aHidB + kO1), AS3(&As[BUF][tid * 8]), 16, 0, 0); \
      __builtin_amdgcn_global_load_lds(AS1(hidc + aHidB + (size_t)64 * 1024 + kO1),                \
                                       AS3(&As[BUF][4096 + tid * 8]), 16, 0, 0);                   \
    }                                                                                              \
    const u16* bp = WgruT + bB + kO;                                                               \
    __builtin_amdgcn_global_load_lds(AS1(bp), AS3(&Bs[BUF][0][tid * 8]), 16, 0, 0);                \
    __builtin_amdgcn_global_load_lds(AS1(bp + (size_t)64 * 1536),                                  \
                                     AS3(&Bs[BUF][0][4096 + tid * 8]), 16, 0, 0);                  \
    __builtin_amdgcn_global_load_lds(AS1(bp + (size_t)1024 * 1536),                                \
                                     AS3(&Bs[BUF][1][tid * 8]), 16, 0, 0);                         \
    __builtin_amdgcn_global_load_lds(AS1(bp + (size_t)1088 * 1536),                                \
                                     AS3(&Bs[BUF][1][4096 + tid * 8]), 16, 0, 0);                  \
    const size_t nOff = ((S) < 8 ? (size_t)2048 * 1536 : (size_t)3072 * 1536);                     \
    __builtin_amdgcn_global_load_lds(AS1(bp + nOff), AS3(&Bs[BUF][2][tid * 8]), 16, 0, 0);         \
    __builtin_amdgcn_global_load_lds(AS1(bp + nOff + (size_t)64 * 1536),                           \
                                     AS3(&Bs[BUF][2][4096 + tid * 8]), 16, 0, 0);                  \
  }

#define GRU_STEP(T, REG3, CUR)                                                                     \
  {                                                                                                \
    bf16x8 af0[4], b00[2], b10[2], b20[2];                                                         \
    _Pragma("unroll") for (int mt = 0; mt < 4; ++mt)                                               \
        af0[mt] = *reinterpret_cast<const bf16x8*>(&As[CUR][(mw + mt * 16 + fr) * 64 + sk0]);      \
    _Pragma("unroll") for (int nt = 0; nt < 2; ++nt) {                                             \
      int rj = (jw + nt * 16 + fr) * 64 + sk0;                                                     \
      b00[nt] = *reinterpret_cast<const bf16x8*>(&Bs[CUR][0][rj]);                                 \
      b10[nt] = *reinterpret_cast<const bf16x8*>(&Bs[CUR][1][rj]);                                 \
      b20[nt] = *reinterpret_cast<const bf16x8*>(&Bs[CUR][2][rj]);                                 \
    }                                                                                              \
    __builtin_amdgcn_s_setprio(1);                                                                 \
    _Pragma("unroll") for (int mt = 0; mt < 4; ++mt)                                               \
        _Pragma("unroll") for (int nt = 0; nt < 2; ++nt) {                                         \
      acc[0][mt][nt] = __builtin_amdgcn_mfma_f32_16x16x32_bf16(af0[mt], b00[nt], acc[0][mt][nt], 0, 0, 0); \
      acc[1][mt][nt] = __builtin_amdgcn_mfma_f32_16x16x32_bf16(af0[mt], b10[nt], acc[1][mt][nt], 0, 0, 0); \
      acc[REG3][mt][nt] = __builtin_amdgcn_mfma_f32_16x16x32_bf16(af0[mt], b20[nt], acc[REG3][mt][nt], 0, 0, 0); \
    }                                                                                              \
    __builtin_amdgcn_s_setprio(0);                                                                 \
    bf16x8 af1[4], b01[2], b11[2], b21[2];                                                         \
    _Pragma("unroll") for (int mt = 0; mt < 4; ++mt)                                               \
        af1[mt] = *reinterpret_cast<const bf16x8*>(&As[CUR][(mw + mt * 16 + fr) * 64 + sk1]);      \
    _Pragma("unroll") for (int nt = 0; nt < 2; ++nt) {                                             \
      int rj = (jw + nt * 16 + fr) * 64 + sk1;                                                     \
      b01[nt] = *reinterpret_cast<const bf16x8*>(&Bs[CUR][0][rj]);                                 \
      b11[nt] = *reinterpret_cast<const bf16x8*>(&Bs[CUR][1][rj]);                                 \
      b21[nt] = *reinterpret_cast<const bf16x8*>(&Bs[CUR][2][rj]);                                 \
    }                                                                                              \
    asm volatile("s_waitcnt lgkmcnt(0)" ::: "memory");                                             \
    __builtin_amdgcn_s_barrier();                                                                  \
    asm volatile("" ::: "memory");                                                                 \
    if ((T) + 2 < 24) { STAGE((T) + 2, CUR) }                                                      \
    __builtin_amdgcn_s_setprio(1);                                                                 \
    _Pragma("unroll") for (int mt = 0; mt < 4; ++mt)                                               \
        _Pragma("unroll") for (int nt = 0; nt < 2; ++nt) {                                         \
      acc[0][mt][nt] = __builtin_amdgcn_mfma_f32_16x16x32_bf16(af1[mt], b01[nt], acc[0][mt][nt], 0, 0, 0); \
      acc[1][mt][nt] = __builtin_amdgcn_mfma_f32_16x16x32_bf16(af1[mt], b11[nt], acc[1][mt][nt], 0, 0, 0); \
      acc[REG3][mt][nt] = __builtin_amdgcn_mfma_f32_16x16x32_bf16(af1[mt], b21[nt], acc[REG3][mt][nt], 0, 0, 0); \
    }                                                                                              \
    __builtin_amdgcn_s_setprio(0);                                                                 \
    if ((T) + 2 < 24)      { asm volatile("s_waitcnt vmcnt(8)" ::: "memory"); }                    \
    else if ((T) + 1 < 24) { asm volatile("s_waitcnt vmcnt(0)" ::: "memory"); }                    \
    __builtin_amdgcn_s_barrier();                                                                  \
    asm volatile("" ::: "memory");                                                                 \
  }

  STAGE(0, 0)
  STAGE(1, 1)
  asm volatile("s_waitcnt vmcnt(8)" ::: "memory");
  __builtin_amdgcn_s_barrier();
  asm volatile("" ::: "memory");
#pragma unroll 1
  for (int T = 0; T < 8; T += 2) {   // tiles 0..7: reg3 = gi_n
    GRU_STEP(T, 2, 0)
    GRU_STEP(T + 1, 2, 1)
  }
#pragma unroll 1
  for (int T = 8; T < 24; T += 2) {  // tiles 8..23: reg3 = gh_n
    GRU_STEP(T, 3, 0)
    GRU_STEP(T + 1, 3, 1)
  }
#undef GRU_STEP
#undef STAGE

  // epilogue: D col=lane&15, row=(lane>>4)*4+reg [m89]
  const int rq = q * 4;
  const float* wt = W_ihf + (size_t)512 * 3072;  // tension row
  float wtr[2], wtz[2], wtn[2], bir[2], biz[2], bin_[2], bhr_[2], bhz_[2], bhn_[2];
#pragma unroll
  for (int nt = 0; nt < 2; ++nt) {
    int j = j0 + jw + nt * 16 + fr;
    wtr[nt] = wt[j]; wtz[nt] = wt[1024 + j]; wtn[nt] = wt[2048 + j];
    bir[nt] = bihf[j]; biz[nt] = bihf[1024 + j]; bin_[nt] = bihf[2048 + j];
    bhr_[nt] = bhhf[j]; bhz_[nt] = bhhf[1024 + j]; bhn_[nt] = bhhf[2048 + j];
  }
#pragma unroll
  for (int mt = 0; mt < 4; ++mt) {
#pragma unroll
    for (int rr = 0; rr < 4; ++rr) {
      int row = m0 + mw + mt * 16 + rq + rr;
      float tv = tension[row] * (1.f / 512.f);
      float wl = fminf(fmaxf(wealthf[row], 0.1f), 2.0f);
      float mod = 0.9f + 0.1f * wl;
#pragma unroll
      for (int nt = 0; nt < 2; ++nt) {
        int j = j0 + jw + nt * 16 + fr;
        float r = sigm(acc[0][mt][nt][rr] + tv * wtr[nt] + bir[nt] + bhr_[nt]);
        float z = sigm(acc[1][mt][nt][rr] + tv * wtz[nt] + biz[nt] + bhz_[nt]);
        float n = fast_tanh(acc[2][mt][nt][rr] + tv * wtn[nt] + bin_[nt]
                            + r * (acc[3][mt][nt][rr] + bhn_[nt]));
        float h = bf2f(hidc[(size_t)row * 1024 + j]);
        float h2 = (1.f - z) * n + z * h;
        h2 = fminf(fmaxf(h2 * mod, -10.f), 10.f);
        hpre[(size_t)row * 1024 + j] = f2bf(h2);
      }
    }
  }
}

// =====================================================================
__global__ void stats_kernel(const u16* __restrict__ hpre, const int* __restrict__ positions,
                             float* __restrict__ fsums) {
  int cc = blockIdx.x, f = blockIdx.y, z = blockIdx.z, t = threadIdx.x;
  int col = cc * 128 + (t & 127);
  int half = t >> 7;
  float st = 0, sp = 0, sm = 0;
  for (int it = 0; it < 128; ++it) {
    int row = (f << 11) + ((z * 128 + it) << 1) + half;
    int p = positions[row];
    float v = bf2f(hpre[(size_t)row * 1024 + col]);
    st += v;
    if (p > 0) sp += v;
    if (p < 0) sm += v;
  }
  atomicAdd(&fsums[(f * 3 + 0) * 1024 + col], st);
  atomicAdd(&fsums[(f * 3 + 1) * 1024 + col], sp);
  atomicAdd(&fsums[(f * 3 + 2) * 1024 + col], sm);
}

__global__ void derive_kernel(const float* __restrict__ fsums, const int* __restrict__ counts,
                              float* __restrict__ mean1, float* __restrict__ mean2,
                              float* __restrict__ fmean, float* __restrict__ gop,
                              float* __restrict__ scal) {
  int c = threadIdx.x;  // 1024
  int cnt1 = 0, cnt2 = 0, cf1[8], cf2[8];
#pragma unroll
  for (int f = 0; f < 8; ++f) {
    cf1[f] = counts[f * 2]; cf2[f] = counts[f * 2 + 1];
    cnt1 += cf1[f]; cnt2 += cf2[f];
  }
  float s1 = 0, s2 = 0;
#pragma unroll
  for (int f = 0; f < 8; ++f) { s1 += fsums[(f * 3 + 1) * 1024 + c]; s2 += fsums[(f * 3 + 2) * 1024 + c]; }
  float m1 = s1 / (float)(cnt1 > 1 ? cnt1 : 1);
  float m2 = s2 / (float)(cnt2 > 1 ? cnt2 : 1);
  float a1 = (cnt1 >= 2) ? 0.1f : 0.f;
  float a2 = (cnt2 >= 2) ? 0.1f : 0.f;
  float g = 0;
#pragma unroll
  for (int f = 0; f < 8; ++f) {
    float fm = (fsums[(f * 3) * 1024 + c]
                + a1 * ((float)cf1[f] * m1 - fsums[(f * 3 + 1) * 1024 + c])
                + a2 * ((float)cf2[f] * m2 - fsums[(f * 3 + 2) * 1024 + c])) * (1.f / 2048.f);
    fmean[f * 1024 + c] = fm;
    g += fm;
  }
  gop[c] = g * 0.125f;
  mean1[c] = m1; mean2[c] = m2;
  if (c == 0) { scal[0] = a1; scal[1] = a2; }
}

__global__ void finalize_kernel(const u16* __restrict__ hpre, const int* __restrict__ positions,
                                const int* __restrict__ step, const float* __restrict__ mean1,
                                const float* __restrict__ mean2, const float* __restrict__ fmean,
                                const float* __restrict__ gop, const float* __restrict__ scal,
                                float* __restrict__ out) {
  int row = blockIdx.x, t = threadIdx.x;
  int p = positions[row];
  float w1 = (p > 0) ? scal[0] : 0.f;
  float w2 = (p < 0) ? scal[1] : 0.f;
  int f = row >> 11, q = row & 2047;
  bool deb = (step[0] > 5) && (q < 512);
  const u16* hrow = hpre + (size_t)row * 1024;
  const float* fmp = fmean + f * 1024;
  float* orow = out + 513 + (size_t)row * 1024;
#pragma unroll
  for (int e = 0; e < 8; ++e) {
    int c = e * 128 + t;
    float h = bf2f(hrow[c]);
    float hgs = h + w1 * (mean1[c] - h) + w2 * (mean2[c] - h);
    float hfs = 0.85f * hgs + 0.15f * fmp[c];
    orow[c] = deb ? (0.85f * hfs + 0.15f * gop[c]) : hfs;
  }
}

__global__ void softmax_kernel(const float* __restrict__ tension, float* __restrict__ weights,
                               float* __restrict__ out) {
  __shared__ float red[1024];
  int t = threadIdx.x;
  float tv[16], mx = -1e30f, sumt = 0.f;
#pragma unroll
  for (int k = 0; k < 16; ++k) {
    tv[k] = tension[t + k * 1024] * (1.f / 512.f);
    mx = fmaxf(mx, tv[k]); sumt += tv[k];
  }
  red[t] = mx; __syncthreads();
  for (int s = 512; s > 0; s >>= 1) { if (t < s) red[t] = fmaxf(red[t], red[t + s]); __syncthreads(); }
  float m = red[0]; __syncthreads();
  red[t] = sumt; __syncthreads();
  for (int s = 512; s > 0; s >>= 1) { if (t < s) red[t] += red[t + s]; __syncthreads(); }
  float tot = red[0]; __syncthreads();
  float ev[16], se = 0.f;
#pragma unroll
  for (int k = 0; k < 16; ++k) { ev[k] = __expf(tv[k] - m); se += ev[k]; }
  red[t] = se; __syncthreads();
  for (int s = 512; s > 0; s >>= 1) { if (t < s) red[t] += red[t + s]; __syncthreads(); }
  float invS = 1.f / red[0];
#pragma unroll
  for (int k = 0; k < 16; ++k) weights[t + k * 1024] = ev[k] * invS;
  if (t == 0) out[512] = tot * (1.f / 16384.f);
}

__global__ void wsum_kernel(const float* __restrict__ weights, const u16* __restrict__ outbf,
                            float* __restrict__ co) {
  int b = blockIdx.x, t = threadIdx.x;
  int c = t * 2;
  float a0 = 0.f, a1 = 0.f;
  int i0 = b * 128;
  for (int i = i0; i < i0 + 128; ++i) {
    float w = weights[i];
    unsigned v = *reinterpret_cast<const unsigned*>(outbf + (size_t)i * 512 + c);
    a0 += w * bf2f(v & 0xffff);
    a1 += w * bf2f(v >> 16);
  }
  atomicAdd(&co[c], a0);
  atomicAdd(&co[c + 1], a1);
}

__global__ void pred_kernel(const float* __restrict__ co, const float* __restrict__ Wof,
                            const float* __restrict__ bof, float* __restrict__ out) {
  __shared__ float cs[512];
  int t = threadIdx.x, n = blockIdx.x * 256 + t;
  cs[t] = co[t]; cs[t + 256] = co[t + 256];
  __syncthreads();
  float acc = bof[n];
  for (int ck = 0; ck < 512; ++ck) acc += cs[ck] * Wof[(size_t)ck * 512 + n];
  out[n] = acc;
}

// =====================================================================
extern "C" void kernel_launch(void* const* d_in, const int* in_sizes, int n_in,
                              void* d_out, int out_size, void* d_ws, size_t ws_size,
                              hipStream_t stream) {
  const float* x      = (const float*)d_in[0];
  const float* hid    = (const float*)d_in[1];
  const float* wealth = (const float*)d_in[2];
  const float* Wa1    = (const float*)d_in[3];
  const float* ba1    = (const float*)d_in[4];
  const float* Wa2    = (const float*)d_in[5];
  const float* ba2    = (const float*)d_in[6];
  const float* Wg1    = (const float*)d_in[7];
  const float* bg1    = (const float*)d_in[8];
  const float* Wg2    = (const float*)d_in[9];
  const float* bg2    = (const float*)d_in[10];
  const float* W_ih   = (const float*)d_in[11];
  const float* W_hh   = (const float*)d_in[12];
  const float* b_ih   = (const float*)d_in[13];
  const float* b_hh   = (const float*)d_in[14];
  const float* Wo     = (const float*)d_in[15];
  const float* bo     = (const float*)d_in[16];
  const int* positions= (const int*)d_in[17];
  const int* step     = (const int*)d_in[18];
  float* out = (float*)d_out;  // [0,512) pred | [512] avg_tension | [513..) new_h

  char* w = (char*)d_ws;
  size_t off = 0;
  auto alloc = [&](size_t bytes) { void* p = w + off; off += (bytes + 255) & ~(size_t)255; return p; };
  u16*   hidc    = (u16*)  alloc((size_t)NC * 1024 * 2);
  u16*   outbf   = (u16*)  alloc((size_t)NC * 512 * 2);
  u16*   hpre    = (u16*)  alloc((size_t)NC * 1024 * 2);
  u16*   WgruT   = (u16*)  alloc((size_t)4096 * 1536 * 2);
  u16*   W1catT  = (u16*)  alloc((size_t)256 * 1024 * 2);
  u16*   W2catT  = (u16*)  alloc((size_t)512 * 256 * 2);
  u16*   t1      = (u16*)  alloc((size_t)NC * 256 * 2);
  // zeroed contiguous: bias1 | co | counts | fsums | tension
  float* bias1   = (float*)alloc(256 * 4);
  float* co      = (float*)alloc(512 * 4);
  int*   counts  = (int*)  alloc(16 * 4);
  float* fsums   = (float*)alloc(8 * 3 * 1024 * 4);
  float* tension = (float*)alloc(NC * 4);
  float* bias2   = (float*)alloc(512 * 4);
  float* weights = (float*)alloc(NC * 4);
  float* mean1   = (float*)alloc(1024 * 4);
  float* mean2   = (float*)alloc(1024 * 4);
  float* gop     = (float*)alloc(1024 * 4);
  float* fmean   = (float*)alloc(8 * 1024 * 4);
  float* scal    = (float*)alloc(8 * 4);

  hipMemsetAsync(bias1, 0, 1024 + 2048 + 256 + 98304 + 65536, stream);

  // cvt (16384) + packT (1248) + smalls (74)
  prep_kernel<<<17706, 256, 0, stream>>>(hid, hidc, W_ih, W_hh, WgruT,
                                         Wa1, Wg1, W1catT, Wa2, Wg2, W2catT,
                                         x, ba1, bg1, bias1, ba2, bg2, bias2,
                                         positions, counts);

  // t1 = relu(h @ W1 + bias1)   M=16384 K=1024 N=256
  gemm_bt<<<dim3(128, 2), 256, 0, stream>>>(hidc, 1024, W1catT, 1024, t1, 256,
                                            bias1, 1, 1024, nullptr);
  // output = t1 @ [Wa2;-Wg2] + (ba2-bg2); fused tension
  gemm_bt<<<dim3(128, 4), 256, 0, stream>>>(t1, 256, W2catT, 256, outbf, 512,
                                            bias2, 3, 256, tension);

  // fused GRU (128x128x4reg tiles, 1024 blocks, 512 threads)
  gemm_gru<<<dim3(128, 8), 512, 0, stream>>>(outbf, hidc, WgruT, W_ih, b_ih, b_hh,
                                             wealth, tension, hpre);

  stats_kernel<<<dim3(8, 8, 8), 256, 0, stream>>>(hpre, positions, fsums);
  derive_kernel<<<1, 1024, 0, stream>>>(fsums, counts, mean1, mean2, fmean, gop, scal);
  finalize_kernel<<<NC, 128, 0, stream>>>(hpre, positions, step, mean1, mean2, fmean, gop,
                                          scal, out);

  softmax_kernel<<<1, 1024, 0, stream>>>(tension, weights, out);
  wsum_kernel<<<128, 256, 0, stream>>>(weights, outbf, co);
  pred_kernel<<<2, 256, 0, stream>>>(co, Wo, bo, out);

  (void)in_sizes; (void)n_in; (void)out_size; (void)ws_size;
}

// Round 3
// 563.796 us; speedup vs baseline: 1.0690x; 1.0243x over previous
//
#include <hip/hip_runtime.h>
#include <stdint.h>

typedef unsigned short u16;
typedef __bf16 bf16x8 __attribute__((ext_vector_type(8)));
typedef float f32x4 __attribute__((ext_vector_type(4)));

// f32 inputs/outputs (verified R2). GEMMs run bf16 MFMA (absmax 0.0156 << 0.05).
// R4: (1) compile-time acc idx, (2) swizzled LDS, (3) occupancy cliffs at 64/128/256 VGPR.
// R5: counted-vmcnt graft on 2-barrier loop = null (regime gate).
// R6: m201-style 128x128x4reg BK=64 dbuf + counted vmcnt: 209.6->185.8us, MfmaUtil 37%.
//     Post-mortem: matrix ~1860cy vs LDS ~1920cy per tile are BALANCED; 37% = poor
//     overlap because 1 block/CU => all 8 waves share the same barriers.
// R7: split into 2 independent 256-thr blocks (128x64 tile, 80KB LDS, 2 blk/CU).
//     Same wave tile + same GRU_STEP schedule; barrier decoupling between blocks.

__device__ __forceinline__ float bf2f(unsigned u) { return __uint_as_float(u << 16); }
__device__ __forceinline__ u16 f2bf(float f) {
  unsigned x = __float_as_uint(f);
  unsigned r = x + 0x7fffu + ((x >> 16) & 1u);
  return (u16)(r >> 16);
}
__device__ __forceinline__ unsigned pack2(float a, float b) {
  return (unsigned)f2bf(a) | ((unsigned)f2bf(b) << 16);
}
__device__ __forceinline__ float sigm(float x) { return 1.f / (1.f + __expf(-x)); }
__device__ __forceinline__ float fast_tanh(float x) {
  float e = __expf(2.f * x);
  return 1.f - 2.f / (e + 1.f);
}

#define AS1(p) ((const __attribute__((address_space(1))) void*)(p))
#define AS3(p) ((__attribute__((address_space(3))) void*)(p))

#define NC 16384

// =====================================================================
// prep: [0,16384) hid f32->bf16 cvt ; [16384,17632) weight transposes ;
// [17632,17706) smalls (bias1/bias2/counts). One launch.
// =====================================================================
__device__ __forceinline__ void packT_body(
    const float* __restrict__ src, int sld, int srow0,
    u16* __restrict__ dst, int dld, int drow0, int koff,
    int remapThresh, int remapAdd, float sgn, int bx, int by,
    float (*tile)[65], int t) {
  const int k0 = by * 64, c0 = bx * 64;
  const int tx = t & 15, ty = t >> 4;
#pragma unroll
  for (int p = 0; p < 4; ++p) {
    int r = ty + p * 16;
    float4 v = *reinterpret_cast<const float4*>(&src[(size_t)(srow0 + k0 + r) * sld + c0 + tx * 4]);
    tile[tx * 4 + 0][r] = v.x;
    tile[tx * 4 + 1][r] = v.y;
    tile[tx * 4 + 2][r] = v.z;
    tile[tx * 4 + 3][r] = v.w;
  }
  __syncthreads();
  const int cl = t >> 2;
  const int kb = (t & 3) * 16;
  int col = c0 + cl;
  int row = drow0 + col + ((col >= remapThresh) ? remapAdd : 0);
  union { u16 o[16]; uint4 v[2]; } u;
#pragma unroll
  for (int e = 0; e < 16; ++e) u.o[e] = f2bf(sgn * tile[cl][kb + e]);
  uint4* d = reinterpret_cast<uint4*>(&dst[(size_t)row * dld + koff + k0 + kb]);
  d[0] = u.v[0]; d[1] = u.v[1];
}

__global__ __launch_bounds__(256) void prep_kernel(
    const float* __restrict__ hid, u16* __restrict__ hidc,
    const float* __restrict__ W_ih, const float* __restrict__ W_hh, u16* __restrict__ WgruT,
    const float* __restrict__ Wa1, const float* __restrict__ Wg1, u16* __restrict__ W1catT,
    const float* __restrict__ Wa2, const float* __restrict__ Wg2, u16* __restrict__ W2catT,
    const float* __restrict__ x, const float* __restrict__ ba1, const float* __restrict__ bg1,
    float* __restrict__ bias1, const float* __restrict__ ba2, const float* __restrict__ bg2,
    float* __restrict__ bias2, const int* __restrict__ positions, int* __restrict__ counts) {
  __shared__ float tile[64][65];
  int b = blockIdx.x, t = threadIdx.x;
  if (b < 16384) {  // cvt: 4 f32 -> 4 bf16 per thread, fully coalesced
    int i = b * 256 + t;
    float4 v = ((const float4*)hid)[i];
    uint2 o; o.x = pack2(v.x, v.y); o.y = pack2(v.z, v.w);
    ((uint2*)hidc)[i] = o;
    return;
  }
  b -= 16384;
  if (b < 768) {  // W_hh (1024x3072) -> WgruT cols 512..; col>=2048 remaps +1024
    packT_body(W_hh, 3072, 0, WgruT, 1536, 0, 512, 2048, 1024, 1.f, b % 48, b / 48, tile, t);
    return;
  }
  b -= 768;
  if (b < 384) {  // W_ih rows 0..511 -> WgruT cols 0..511
    packT_body(W_ih, 3072, 0, WgruT, 1536, 0, 0, 1 << 30, 0, 1.f, b % 48, b / 48, tile, t);
    return;
  }
  b -= 384;
  if (b < 32) { packT_body(Wa1, 128, 512, W1catT, 1024, 0, 0, 1 << 30, 0, 1.f, b % 2, b / 2, tile, t); return; }
  b -= 32;
  if (b < 32) { packT_body(Wg1, 128, 512, W1catT, 1024, 128, 0, 1 << 30, 0, 1.f, b % 2, b / 2, tile, t); return; }
  b -= 32;
  if (b < 16) { packT_body(Wa2, 512, 0, W2catT, 256, 0, 0, 1 << 30, 0, 1.f, b % 8, b / 8, tile, t); return; }
  b -= 16;
  if (b < 16) { packT_body(Wg2, 512, 0, W2catT, 256, 0, 128, 1 << 30, 0, -1.f, b % 8, b / 8, tile, t); return; }
  b -= 16;
  if (b < 8) {  // bias1, k-split over 8 blocks, atomic into zeroed buf
    const float* W = (t < 128) ? Wa1 : Wg1;
    int cc = t & 127;
    float acc = 0.f;
    int k0 = b * 64;
    for (int k = k0; k < k0 + 64; ++k) acc += x[k] * W[(size_t)k * 128 + cc];
    if (b == 0) acc += (t < 128) ? ba1[cc] : bg1[cc];
    atomicAdd(&bias1[t], acc);
    return;
  }
  b -= 8;
  if (b < 2) { int n = b * 256 + t; bias2[n] = ba2[n] - bg2[n]; return; }
  b -= 2;
  {
    int i = b * 256 + t;
    int p = positions[i], f = i >> 11;
    if (p > 0) atomicAdd(&counts[f * 2], 1);
    else if (p < 0) atomicAdd(&counts[f * 2 + 1], 1);
  }
}

// =====================================================================
// bf16 MFMA GEMM, 128x128, BK=32, XOR-swizzled LDS (slot = q ^ ((row>>1)&3)).
// Triple-buffered, depth-2 prefetch, counted vmcnt. epi 1: +bias,relu ;
// epi 3: +bias + fused per-row sum-of-squares -> tension.
// =====================================================================
__global__ __launch_bounds__(256) void gemm_bt(
    const u16* __restrict__ A, int lda,
    const u16* __restrict__ Bt, int ldb,
    u16* __restrict__ C, int ldc,
    const float* __restrict__ bias, int epi, int K,
    float* __restrict__ tension) {
  __shared__ __align__(16) u16 As[3][128 * 32];
  __shared__ __align__(16) u16 Bs[3][128 * 32];
  const int tid = threadIdx.x;
  const int m0 = blockIdx.x * 128;
  const int n0 = blockIdx.y * 128;
  f32x4 acc[4][4] = {};
  const int lane = tid & 63;
  const int w = tid >> 6;
  const int mw = (w & 1) * 64, nw = (w >> 1) * 64;
  const int fr = lane & 15;
  const int q = lane >> 4;
  const int ar0 = tid >> 2;                     // rows 0..63 (chunk tid), +64 for chunk tid+256
  const int ag = ((tid & 3) ^ ((ar0 >> 1) & 3)) * 8;  // (row+64)>>1 keeps same &3 -> ag reused

  const u16* aB0 = A + (size_t)(m0 + ar0) * lda + ag;
  const u16* aB1 = A + (size_t)(m0 + ar0 + 64) * lda + ag;
  const u16* bB0 = Bt + (size_t)(n0 + ar0) * ldb + ag;
  const u16* bB1 = Bt + (size_t)(n0 + ar0 + 64) * ldb + ag;

  auto stage = [&](int kk, int buf) {
    __builtin_amdgcn_global_load_lds(AS1(aB0 + kk), AS3(&As[buf][tid * 8]), 16, 0, 0);
    __builtin_amdgcn_global_load_lds(AS1(aB1 + kk), AS3(&As[buf][(tid + 256) * 8]), 16, 0, 0);
    __builtin_amdgcn_global_load_lds(AS1(bB0 + kk), AS3(&Bs[buf][tid * 8]), 16, 0, 0);
    __builtin_amdgcn_global_load_lds(AS1(bB1 + kk), AS3(&Bs[buf][(tid + 256) * 8]), 16, 0, 0);
  };

  const int NT = K >> 5;   // >= 8 for all calls
  stage(0, 0);
  stage(32, 1);
  int cur = 0, nxt = 1, nx2 = 2;
#pragma unroll 1
  for (int t = 0; t < NT; ++t) {
    if (t + 2 < NT) stage((t + 2) * 32, nx2);
    const int rem = NT - 1 - t;  // tiles newer than t in flight
    if (rem >= 2)      asm volatile("s_waitcnt vmcnt(8)" ::: "memory");
    else if (rem == 1) asm volatile("s_waitcnt vmcnt(4)" ::: "memory");
    else               asm volatile("s_waitcnt vmcnt(0)" ::: "memory");
    __builtin_amdgcn_s_barrier();          // tile t fully in LDS (all waves)
    asm volatile("" ::: "memory");
    bf16x8 af[4], bfv[4];
#pragma unroll
    for (int mt = 0; mt < 4; ++mt) {
      int r = mw + mt * 16 + fr;
      af[mt] = *reinterpret_cast<const bf16x8*>(&As[cur][r * 32 + ((q ^ ((r >> 1) & 3)) * 8)]);
    }
#pragma unroll
    for (int nt = 0; nt < 4; ++nt) {
      int r = nw + nt * 16 + fr;
      bfv[nt] = *reinterpret_cast<const bf16x8*>(&Bs[cur][r * 32 + ((q ^ ((r >> 1) & 3)) * 8)]);
    }
    __builtin_amdgcn_s_setprio(1);
#pragma unroll
    for (int mt = 0; mt < 4; ++mt)
#pragma unroll
      for (int nt = 0; nt < 4; ++nt)
        acc[mt][nt] = __builtin_amdgcn_mfma_f32_16x16x32_bf16(af[mt], bfv[nt], acc[mt][nt], 0, 0, 0);
    __builtin_amdgcn_s_setprio(0);
    asm volatile("s_waitcnt lgkmcnt(0)" ::: "memory");  // my ds_reads retired
    __builtin_amdgcn_s_barrier();          // buf[cur] safe to overwrite at t+1
    int tmp = cur; cur = nxt; nxt = nx2; nx2 = tmp;
  }
  const int rq = q * 4;  // D: col=lane&15, row=rq+reg [m89]
#pragma unroll
  for (int mt = 0; mt < 4; ++mt) {
    float srow[4] = {0.f, 0.f, 0.f, 0.f};
#pragma unroll
    for (int nt = 0; nt < 4; ++nt) {
      int col = n0 + nw + nt * 16 + fr;
      f32x4 v = acc[mt][nt];
#pragma unroll
      for (int r = 0; r < 4; ++r) {
        int row = m0 + mw + mt * 16 + rq + r;
        float val = v[r] + bias[col];
        if (epi == 1) val = val > 0.f ? val : 0.f;
        else srow[r] += val * val;
        C[(size_t)row * ldc + col] = f2bf(val);
      }
    }
    if (epi == 3) {
#pragma unroll
      for (int r = 0; r < 4; ++r) {
        float s = srow[r];
        s += __shfl_xor(s, 1, 16); s += __shfl_xor(s, 2, 16);
        s += __shfl_xor(s, 4, 16); s += __shfl_xor(s, 8, 16);
        if (fr == 0) atomicAdd(&tension[m0 + mw + mt * 16 + rq + r], s);
      }
    }
  }
}

// =====================================================================
// R7 fused GRU. 256 threads / 4 waves; block tile 128 rows x 64 j-cols x
// 4 regions; BK=64; wave = 64 rows x 32 j x 4 reg (acc[4][4][2] = 128 VGPR).
// LDS: dbuf As[2][128][64] (32KB) + Bs[2][3][64][64] (48KB) = 80KB -> 2 blk/CU.
// Two independent blocks per CU decouple barriers (m114 overlap mechanism).
// Layout [row][64] u16: slot' = slot ^ (row&7) via pre-swizzled global source.
// Per K-tile: ds ks0 | 24 MFMA | ds ks1 | lgkm0+bar | stage t+2 (10 gld)
// | 24 MFMA | vmcnt(10)+bar. Counted vmcnt in steady state (T3+T4).
// Tiles 0..7: A=outbf (K 0..511), reg3=gi_n(rows 2048+). Tiles 8..23: A=hidc,
// reg3=gh_n(rows 3072+). WgruT k index = s*64 uniformly.
// =====================================================================
__global__ __launch_bounds__(256, 2) void gemm_gru(
    const u16* __restrict__ outbf, const u16* __restrict__ hidc,
    const u16* __restrict__ WgruT,
    const float* __restrict__ W_ihf, const float* __restrict__ bihf,
    const float* __restrict__ bhhf, const float* __restrict__ wealthf,
    const float* __restrict__ tension, u16* __restrict__ hpre) {
  __shared__ __align__(16) u16 As[2][128 * 64];
  __shared__ __align__(16) u16 Bs[2][3][64 * 64];
  const int tid = threadIdx.x;
  const int m0 = blockIdx.x * 128;
  const int j0 = blockIdx.y * 64;
  f32x4 acc[4][4][2] = {};  // [region][mt][nt]
  const int lane = tid & 63;
  const int w = tid >> 6;
  const int mw = (w & 1) * 64, jw = (w >> 1) * 32;
  const int fr = lane & 15;
  const int q = lane >> 4;
  // staging: chunk = tid (row = tid>>3 in [0,32), slot = tid&7); extra rows via
  // +32*it (keeps row&7). global source k-group pre-swizzled: gslot = slot^(row&7).
  const int rowl = tid >> 3;
  const int koffT = ((tid & 7) ^ (rowl & 7)) * 8;
  const size_t aOutB = (size_t)(m0 + rowl) * 512 + koffT;
  const size_t aHidB = (size_t)(m0 + rowl) * 1024 + koffT;
  const size_t bB    = (size_t)(j0 + rowl) * 1536 + koffT;
  // frag-read slot offsets (u16): slot' = (ks*4+q)^(fr&7), *8 elems
  const int f7 = fr & 7;
  const int sk0 = (q ^ f7) * 8;
  const int sk1 = ((4 + q) ^ f7) * 8;

#define STAGE(S, BUF)                                                                              \
  {                                                                                                \
    const size_t kO = (size_t)(S) * 64;                                                            \
    if ((S) < 8) {                                                                                 \
      _Pragma("unroll") for (int it = 0; it < 4; ++it)                                             \
          __builtin_amdgcn_global_load_lds(AS1(outbf + aOutB + (size_t)(32 * it) * 512 + kO),      \
                                           AS3(&As[BUF][tid * 8 + it * 2048]), 16, 0, 0);          \
    } else {                                                                                       \
      const size_t kO1 = (size_t)((S) - 8) * 64;                                                   \
      _Pragma("unroll") for (int it = 0; it < 4; ++it)                                             \
          __builtin_amdgcn_global_load_lds(AS1(hidc + aHidB + (size_t)(32 * it) * 1024 + kO1),     \
                                           AS3(&As[BUF][tid * 8 + it * 2048]), 16, 0, 0);          \
    }                                                                                              \
    const u16* bp = WgruT + bB + kO;                                                               \
    __builtin_amdgcn_global_load_lds(AS1(bp), AS3(&Bs[BUF][0][tid * 8]), 16, 0, 0);                \
    __builtin_amdgcn_global_load_lds(AS1(bp + (size_t)32 * 1536),                                  \
                                     AS3(&Bs[BUF][0][tid * 8 + 2048]), 16, 0, 0);                  \
    __builtin_amdgcn_global_load_lds(AS1(bp + (size_t)1024 * 1536),                                \
                                     AS3(&Bs[BUF][1][tid * 8]), 16, 0, 0);                         \
    __builtin_amdgcn_global_load_lds(AS1(bp + (size_t)1056 * 1536),                                \
                                     AS3(&Bs[BUF][1][tid * 8 + 2048]), 16, 0, 0);                  \
    const size_t nOff = ((S) < 8 ? (size_t)2048 * 1536 : (size_t)3072 * 1536);                     \
    __builtin_amdgcn_global_load_lds(AS1(bp + nOff), AS3(&Bs[BUF][2][tid * 8]), 16, 0, 0);         \
    __builtin_amdgcn_global_load_lds(AS1(bp + nOff + (size_t)32 * 1536),                           \
                                     AS3(&Bs[BUF][2][tid * 8 + 2048]), 16, 0, 0);                  \
  }

#define GRU_STEP(T, REG3, CUR)                                                                     \
  {                                                                                                \
    bf16x8 af0[4], b00[2], b10[2], b20[2];                                                         \
    _Pragma("unroll") for (int mt = 0; mt < 4; ++mt)                                               \
        af0[mt] = *reinterpret_cast<const bf16x8*>(&As[CUR][(mw + mt * 16 + fr) * 64 + sk0]);      \
    _Pragma("unroll") for (int nt = 0; nt < 2; ++nt) {                                             \
      int rj = (jw + nt * 16 + fr) * 64 + sk0;                                                     \
      b00[nt] = *reinterpret_cast<const bf16x8*>(&Bs[CUR][0][rj]);                                 \
      b10[nt] = *reinterpret_cast<const bf16x8*>(&Bs[CUR][1][rj]);                                 \
      b20[nt] = *reinterpret_cast<const bf16x8*>(&Bs[CUR][2][rj]);                                 \
    }                                                                                              \
    __builtin_amdgcn_s_setprio(1);                                                                 \
    _Pragma("unroll") for (int mt = 0; mt < 4; ++mt)                                               \
        _Pragma("unroll") for (int nt = 0; nt < 2; ++nt) {                                         \
      acc[0][mt][nt] = __builtin_amdgcn_mfma_f32_16x16x32_bf16(af0[mt], b00[nt], acc[0][mt][nt], 0, 0, 0); \
      acc[1][mt][nt] = __builtin_amdgcn_mfma_f32_16x16x32_bf16(af0[mt], b10[nt], acc[1][mt][nt], 0, 0, 0); \
      acc[REG3][mt][nt] = __builtin_amdgcn_mfma_f32_16x16x32_bf16(af0[mt], b20[nt], acc[REG3][mt][nt], 0, 0, 0); \
    }                                                                                              \
    __builtin_amdgcn_s_setprio(0);                                                                 \
    bf16x8 af1[4], b01[2], b11[2], b21[2];                                                         \
    _Pragma("unroll") for (int mt = 0; mt < 4; ++mt)                                               \
        af1[mt] = *reinterpret_cast<const bf16x8*>(&As[CUR][(mw + mt * 16 + fr) * 64 + sk1]);      \
    _Pragma("unroll") for (int nt = 0; nt < 2; ++nt) {                                             \
      int rj = (jw + nt * 16 + fr) * 64 + sk1;                                                     \
      b01[nt] = *reinterpret_cast<const bf16x8*>(&Bs[CUR][0][rj]);                                 \
      b11[nt] = *reinterpret_cast<const bf16x8*>(&Bs[CUR][1][rj]);                                 \
      b21[nt] = *reinterpret_cast<const bf16x8*>(&Bs[CUR][2][rj]);                                 \
    }                                                                                              \
    asm volatile("s_waitcnt lgkmcnt(0)" ::: "memory");                                             \
    __builtin_amdgcn_s_barrier();                                                                  \
    asm volatile("" ::: "memory");                                                                 \
    if ((T) + 2 < 24) { STAGE((T) + 2, CUR) }                                                      \
    __builtin_amdgcn_s_setprio(1);                                                                 \
    _Pragma("unroll") for (int mt = 0; mt < 4; ++mt)                                               \
        _Pragma("unroll") for (int nt = 0; nt < 2; ++nt) {                                         \
      acc[0][mt][nt] = __builtin_amdgcn_mfma_f32_16x16x32_bf16(af1[mt], b01[nt], acc[0][mt][nt], 0, 0, 0); \
      acc[1][mt][nt] = __builtin_amdgcn_mfma_f32_16x16x32_bf16(af1[mt], b11[nt], acc[1][mt][nt], 0, 0, 0); \
      acc[REG3][mt][nt] = __builtin_amdgcn_mfma_f32_16x16x32_bf16(af1[mt], b21[nt], acc[REG3][mt][nt], 0, 0, 0); \
    }                                                                                              \
    __builtin_amdgcn_s_setprio(0);                                                                 \
    if ((T) + 2 < 24)      { asm volatile("s_waitcnt vmcnt(10)" ::: "memory"); }                   \
    else if ((T) + 1 < 24) { asm volatile("s_waitcnt vmcnt(0)" ::: "memory"); }                    \
    __builtin_amdgcn_s_barrier();                                                                  \
    asm volatile("" ::: "memory");                                                                 \
  }

  STAGE(0, 0)
  STAGE(1, 1)
  asm volatile("s_waitcnt vmcnt(10)" ::: "memory");
  __builtin_amdgcn_s_barrier();
  asm volatile("" ::: "memory");
#pragma unroll 1
  for (int T = 0; T < 8; T += 2) {   // tiles 0..7: reg3 = gi_n
    GRU_STEP(T, 2, 0)
    GRU_STEP(T + 1, 2, 1)
  }
#pragma unroll 1
  for (int T = 8; T < 24; T += 2) {  // tiles 8..23: reg3 = gh_n
    GRU_STEP(T, 3, 0)
    GRU_STEP(T + 1, 3, 1)
  }
#undef GRU_STEP
#undef STAGE

  // epilogue: D col=lane&15, row=(lane>>4)*4+reg [m89]
  const int rq = q * 4;
  const float* wt = W_ihf + (size_t)512 * 3072;  // tension row
  float wtr[2], wtz[2], wtn[2], bir[2], biz[2], bin_[2], bhr_[2], bhz_[2], bhn_[2];
#pragma unroll
  for (int nt = 0; nt < 2; ++nt) {
    int j = j0 + jw + nt * 16 + fr;
    wtr[nt] = wt[j]; wtz[nt] = wt[1024 + j]; wtn[nt] = wt[2048 + j];
    bir[nt] = bihf[j]; biz[nt] = bihf[1024 + j]; bin_[nt] = bihf[2048 + j];
    bhr_[nt] = bhhf[j]; bhz_[nt] = bhhf[1024 + j]; bhn_[nt] = bhhf[2048 + j];
  }
#pragma unroll
  for (int mt = 0; mt < 4; ++mt) {
#pragma unroll
    for (int rr = 0; rr < 4; ++rr) {
      int row = m0 + mw + mt * 16 + rq + rr;
      float tv = tension[row] * (1.f / 512.f);
      float wl = fminf(fmaxf(wealthf[row], 0.1f), 2.0f);
      float mod = 0.9f + 0.1f * wl;
#pragma unroll
      for (int nt = 0; nt < 2; ++nt) {
        int j = j0 + jw + nt * 16 + fr;
        float r = sigm(acc[0][mt][nt][rr] + tv * wtr[nt] + bir[nt] + bhr_[nt]);
        float z = sigm(acc[1][mt][nt][rr] + tv * wtz[nt] + biz[nt] + bhz_[nt]);
        float n = fast_tanh(acc[2][mt][nt][rr] + tv * wtn[nt] + bin_[nt]
                            + r * (acc[3][mt][nt][rr] + bhn_[nt]));
        float h = bf2f(hidc[(size_t)row * 1024 + j]);
        float h2 = (1.f - z) * n + z * h;
        h2 = fminf(fmaxf(h2 * mod, -10.f), 10.f);
        hpre[(size_t)row * 1024 + j] = f2bf(h2);
      }
    }
  }
}

// =====================================================================
__global__ void stats_kernel(const u16* __restrict__ hpre, const int* __restrict__ positions,
                             float* __restrict__ fsums) {
  int cc = blockIdx.x, f = blockIdx.y, z = blockIdx.z, t = threadIdx.x;
  int col = cc * 128 + (t & 127);
  int half = t >> 7;
  float st = 0, sp = 0, sm = 0;
  for (int it = 0; it < 128; ++it) {
    int row = (f << 11) + ((z * 128 + it) << 1) + half;
    int p = positions[row];
    float v = bf2f(hpre[(size_t)row * 1024 + col]);
    st += v;
    if (p > 0) sp += v;
    if (p < 0) sm += v;
  }
  atomicAdd(&fsums[(f * 3 + 0) * 1024 + col], st);
  atomicAdd(&fsums[(f * 3 + 1) * 1024 + col], sp);
  atomicAdd(&fsums[(f * 3 + 2) * 1024 + col], sm);
}

__global__ void derive_kernel(const float* __restrict__ fsums, const int* __restrict__ counts,
                              float* __restrict__ mean1, float* __restrict__ mean2,
                              float* __restrict__ fmean, float* __restrict__ gop,
                              float* __restrict__ scal) {
  int c = threadIdx.x;  // 1024
  int cnt1 = 0, cnt2 = 0, cf1[8], cf2[8];
#pragma unroll
  for (int f = 0; f < 8; ++f) {
    cf1[f] = counts[f * 2]; cf2[f] = counts[f * 2 + 1];
    cnt1 += cf1[f]; cnt2 += cf2[f];
  }
  float s1 = 0, s2 = 0;
#pragma unroll
  for (int f = 0; f < 8; ++f) { s1 += fsums[(f * 3 + 1) * 1024 + c]; s2 += fsums[(f * 3 + 2) * 1024 + c]; }
  float m1 = s1 / (float)(cnt1 > 1 ? cnt1 : 1);
  float m2 = s2 / (float)(cnt2 > 1 ? cnt2 : 1);
  float a1 = (cnt1 >= 2) ? 0.1f : 0.f;
  float a2 = (cnt2 >= 2) ? 0.1f : 0.f;
  float g = 0;
#pragma unroll
  for (int f = 0; f < 8; ++f) {
    float fm = (fsums[(f * 3) * 1024 + c]
                + a1 * ((float)cf1[f] * m1 - fsums[(f * 3 + 1) * 1024 + c])
                + a2 * ((float)cf2[f] * m2 - fsums[(f * 3 + 2) * 1024 + c])) * (1.f / 2048.f);
    fmean[f * 1024 + c] = fm;
    g += fm;
  }
  gop[c] = g * 0.125f;
  mean1[c] = m1; mean2[c] = m2;
  if (c == 0) { scal[0] = a1; scal[1] = a2; }
}

__global__ void finalize_kernel(const u16* __restrict__ hpre, const int* __restrict__ positions,
                                const int* __restrict__ step, const float* __restrict__ mean1,
                                const float* __restrict__ mean2, const float* __restrict__ fmean,
                                const float* __restrict__ gop, const float* __restrict__ scal,
                                float* __restrict__ out) {
  int row = blockIdx.x, t = threadIdx.x;
  int p = positions[row];
  float w1 = (p > 0) ? scal[0] : 0.f;
  float w2 = (p < 0) ? scal[1] : 0.f;
  int f = row >> 11, q = row & 2047;
  bool deb = (step[0] > 5) && (q < 512);
  const u16* hrow = hpre + (size_t)row * 1024;
  const float* fmp = fmean + f * 1024;
  float* orow = out + 513 + (size_t)row * 1024;
#pragma unroll
  for (int e = 0; e < 8; ++e) {
    int c = e * 128 + t;
    float h = bf2f(hrow[c]);
    float hgs = h + w1 * (mean1[c] - h) + w2 * (mean2[c] - h);
    float hfs = 0.85f * hgs + 0.15f * fmp[c];
    orow[c] = deb ? (0.85f * hfs + 0.15f * gop[c]) : hfs;
  }
}

__global__ void softmax_kernel(const float* __restrict__ tension, float* __restrict__ weights,
                               float* __restrict__ out) {
  __shared__ float red[1024];
  int t = threadIdx.x;
  float tv[16], mx = -1e30f, sumt = 0.f;
#pragma unroll
  for (int k = 0; k < 16; ++k) {
    tv[k] = tension[t + k * 1024] * (1.f / 512.f);
    mx = fmaxf(mx, tv[k]); sumt += tv[k];
  }
  red[t] = mx; __syncthreads();
  for (int s = 512; s > 0; s >>= 1) { if (t < s) red[t] = fmaxf(red[t], red[t + s]); __syncthreads(); }
  float m = red[0]; __syncthreads();
  red[t] = sumt; __syncthreads();
  for (int s = 512; s > 0; s >>= 1) { if (t < s) red[t] += red[t + s]; __syncthreads(); }
  float tot = red[0]; __syncthreads();
  float ev[16], se = 0.f;
#pragma unroll
  for (int k = 0; k < 16; ++k) { ev[k] = __expf(tv[k] - m); se += ev[k]; }
  red[t] = se; __syncthreads();
  for (int s = 512; s > 0; s >>= 1) { if (t < s) red[t] += red[t + s]; __syncthreads(); }
  float invS = 1.f / red[0];
#pragma unroll
  for (int k = 0; k < 16; ++k) weights[t + k * 1024] = ev[k] * invS;
  if (t == 0) out[512] = tot * (1.f / 16384.f);
}

__global__ void wsum_kernel(const float* __restrict__ weights, const u16* __restrict__ outbf,
                            float* __restrict__ co) {
  int b = blockIdx.x, t = threadIdx.x;
  int c = t * 2;
  float a0 = 0.f, a1 = 0.f;
  int i0 = b * 128;
  for (int i = i0; i < i0 + 128; ++i) {
    float w = weights[i];
    unsigned v = *reinterpret_cast<const unsigned*>(outbf + (size_t)i * 512 + c);
    a0 += w * bf2f(v & 0xffff);
    a1 += w * bf2f(v >> 16);
  }
  atomicAdd(&co[c], a0);
  atomicAdd(&co[c + 1], a1);
}

__global__ void pred_kernel(const float* __restrict__ co, const float* __restrict__ Wof,
                            const float* __restrict__ bof, float* __restrict__ out) {
  __shared__ float cs[512];
  int t = threadIdx.x, n = blockIdx.x * 256 + t;
  cs[t] = co[t]; cs[t + 256] = co[t + 256];
  __syncthreads();
  float acc = bof[n];
  for (int ck = 0; ck < 512; ++ck) acc += cs[ck] * Wof[(size_t)ck * 512 + n];
  out[n] = acc;
}

// =====================================================================
extern "C" void kernel_launch(void* const* d_in, const int* in_sizes, int n_in,
                              void* d_out, int out_size, void* d_ws, size_t ws_size,
                              hipStream_t stream) {
  const float* x      = (const float*)d_in[0];
  const float* hid    = (const float*)d_in[1];
  const float* wealth = (const float*)d_in[2];
  const float* Wa1    = (const float*)d_in[3];
  const float* ba1    = (const float*)d_in[4];
  const float* Wa2    = (const float*)d_in[5];
  const float* ba2    = (const float*)d_in[6];
  const float* Wg1    = (const float*)d_in[7];
  const float* bg1    = (const float*)d_in[8];
  const float* Wg2    = (const float*)d_in[9];
  const float* bg2    = (const float*)d_in[10];
  const float* W_ih   = (const float*)d_in[11];
  const float* W_hh   = (const float*)d_in[12];
  const float* b_ih   = (const float*)d_in[13];
  const float* b_hh   = (const float*)d_in[14];
  const float* Wo     = (const float*)d_in[15];
  const float* bo     = (const float*)d_in[16];
  const int* positions= (const int*)d_in[17];
  const int* step     = (const int*)d_in[18];
  float* out = (float*)d_out;  // [0,512) pred | [512] avg_tension | [513..) new_h

  char* w = (char*)d_ws;
  size_t off = 0;
  auto alloc = [&](size_t bytes) { void* p = w + off; off += (bytes + 255) & ~(size_t)255; return p; };
  u16*   hidc    = (u16*)  alloc((size_t)NC * 1024 * 2);
  u16*   outbf   = (u16*)  alloc((size_t)NC * 512 * 2);
  u16*   hpre    = (u16*)  alloc((size_t)NC * 1024 * 2);
  u16*   WgruT   = (u16*)  alloc((size_t)4096 * 1536 * 2);
  u16*   W1catT  = (u16*)  alloc((size_t)256 * 1024 * 2);
  u16*   W2catT  = (u16*)  alloc((size_t)512 * 256 * 2);
  u16*   t1      = (u16*)  alloc((size_t)NC * 256 * 2);
  // zeroed contiguous: bias1 | co | counts | fsums | tension
  float* bias1   = (float*)alloc(256 * 4);
  float* co      = (float*)alloc(512 * 4);
  int*   counts  = (int*)  alloc(16 * 4);
  float* fsums   = (float*)alloc(8 * 3 * 1024 * 4);
  float* tension = (float*)alloc(NC * 4);
  float* bias2   = (float*)alloc(512 * 4);
  float* weights = (float*)alloc(NC * 4);
  float* mean1   = (float*)alloc(1024 * 4);
  float* mean2   = (float*)alloc(1024 * 4);
  float* gop     = (float*)alloc(1024 * 4);
  float* fmean   = (float*)alloc(8 * 1024 * 4);
  float* scal    = (float*)alloc(8 * 4);

  hipMemsetAsync(bias1, 0, 1024 + 2048 + 256 + 98304 + 65536, stream);

  // cvt (16384) + packT (1248) + smalls (74)
  prep_kernel<<<17706, 256, 0, stream>>>(hid, hidc, W_ih, W_hh, WgruT,
                                         Wa1, Wg1, W1catT, Wa2, Wg2, W2catT,
                                         x, ba1, bg1, bias1, ba2, bg2, bias2,
                                         positions, counts);

  // t1 = relu(h @ W1 + bias1)   M=16384 K=1024 N=256
  gemm_bt<<<dim3(128, 2), 256, 0, stream>>>(hidc, 1024, W1catT, 1024, t1, 256,
                                            bias1, 1, 1024, nullptr);
  // output = t1 @ [Wa2;-Wg2] + (ba2-bg2); fused tension
  gemm_bt<<<dim3(128, 4), 256, 0, stream>>>(t1, 256, W2catT, 256, outbf, 512,
                                            bias2, 3, 256, tension);

  // fused GRU (128x64 tiles, 2048 blocks, 256 threads, 2 blocks/CU)
  gemm_gru<<<dim3(128, 16), 256, 0, stream>>>(outbf, hidc, WgruT, W_ih, b_ih, b_hh,
                                              wealth, tension, hpre);

  stats_kernel<<<dim3(8, 8, 8), 256, 0, stream>>>(hpre, positions, fsums);
  derive_kernel<<<1, 1024, 0, stream>>>(fsums, counts, mean1, mean2, fmean, gop, scal);
  finalize_kernel<<<NC, 128, 0, stream>>>(hpre, positions, step, mean1, mean2, fmean, gop,
                                          scal, out);

  softmax_kernel<<<1, 1024, 0, stream>>>(tension, weights, out);
  wsum_kernel<<<128, 256, 0, stream>>>(weights, outbf, co);
  pred_kernel<<<2, 256, 0, stream>>>(co, Wo, bo, out);

  (void)in_sizes; (void)n_in; (void)out_size; (void)ws_size;
}

// Round 4
// 563.661 us; speedup vs baseline: 1.0692x; 1.0002x over previous
//
#include <hip/hip_runtime.h>
#include <stdint.h>

typedef unsigned short u16;
typedef __bf16 bf16x8 __attribute__((ext_vector_type(8)));
typedef float f32x4 __attribute__((ext_vector_type(4)));

// f32 inputs/outputs (verified R2). GEMMs run bf16 MFMA (absmax 0.0156 << 0.05).
// R4: (1) compile-time acc idx, (2) swizzled LDS, (3) occupancy cliffs at 64/128/256 VGPR.
// R5: counted-vmcnt graft on 2-barrier loop = null (regime gate).
// R6: m201-style 128x128 BK=64 dbuf + counted vmcnt: 209.6->185.8us.
// R7: 2 independent 256-thr blocks/CU (128x64 tile, 80KB LDS): gemm_gru < 176us.
//     New top kernel: prep at 176us, 500GB/s, VALU 1.3% => LATENCY-BOUND (1 load/thread).
// R8: cvt path 16384 tiny blocks -> 2048 blocks x 8 unrolled float4 loads (8KB/wave in
//     flight); finalize 16384x128 -> 2048x256 with 8 rows/block. GEMMs untouched.

__device__ __forceinline__ float bf2f(unsigned u) { return __uint_as_float(u << 16); }
__device__ __forceinline__ u16 f2bf(float f) {
  unsigned x = __float_as_uint(f);
  unsigned r = x + 0x7fffu + ((x >> 16) & 1u);
  return (u16)(r >> 16);
}
__device__ __forceinline__ unsigned pack2(float a, float b) {
  return (unsigned)f2bf(a) | ((unsigned)f2bf(b) << 16);
}
__device__ __forceinline__ float sigm(float x) { return 1.f / (1.f + __expf(-x)); }
__device__ __forceinline__ float fast_tanh(float x) {
  float e = __expf(2.f * x);
  return 1.f - 2.f / (e + 1.f);
}

#define AS1(p) ((const __attribute__((address_space(1))) void*)(p))
#define AS3(p) ((__attribute__((address_space(3))) void*)(p))

#define NC 16384

// =====================================================================
// prep: [0,2048) hid f32->bf16 cvt (8 chunks/thread) ; [2048,3296) weight
// transposes ; [3296,3370) smalls (bias1/bias2/counts). One launch.
// =====================================================================
__device__ __forceinline__ void packT_body(
    const float* __restrict__ src, int sld, int srow0,
    u16* __restrict__ dst, int dld, int drow0, int koff,
    int remapThresh, int remapAdd, float sgn, int bx, int by,
    float (*tile)[65], int t) {
  const int k0 = by * 64, c0 = bx * 64;
  const int tx = t & 15, ty = t >> 4;
#pragma unroll
  for (int p = 0; p < 4; ++p) {
    int r = ty + p * 16;
    float4 v = *reinterpret_cast<const float4*>(&src[(size_t)(srow0 + k0 + r) * sld + c0 + tx * 4]);
    tile[tx * 4 + 0][r] = v.x;
    tile[tx * 4 + 1][r] = v.y;
    tile[tx * 4 + 2][r] = v.z;
    tile[tx * 4 + 3][r] = v.w;
  }
  __syncthreads();
  const int cl = t >> 2;
  const int kb = (t & 3) * 16;
  int col = c0 + cl;
  int row = drow0 + col + ((col >= remapThresh) ? remapAdd : 0);
  union { u16 o[16]; uint4 v[2]; } u;
#pragma unroll
  for (int e = 0; e < 16; ++e) u.o[e] = f2bf(sgn * tile[cl][kb + e]);
  uint4* d = reinterpret_cast<uint4*>(&dst[(size_t)row * dld + koff + k0 + kb]);
  d[0] = u.v[0]; d[1] = u.v[1];
}

__global__ __launch_bounds__(256) void prep_kernel(
    const float* __restrict__ hid, u16* __restrict__ hidc,
    const float* __restrict__ W_ih, const float* __restrict__ W_hh, u16* __restrict__ WgruT,
    const float* __restrict__ Wa1, const float* __restrict__ Wg1, u16* __restrict__ W1catT,
    const float* __restrict__ Wa2, const float* __restrict__ Wg2, u16* __restrict__ W2catT,
    const float* __restrict__ x, const float* __restrict__ ba1, const float* __restrict__ bg1,
    float* __restrict__ bias1, const float* __restrict__ ba2, const float* __restrict__ bg2,
    float* __restrict__ bias2, const int* __restrict__ positions, int* __restrict__ counts) {
  __shared__ float tile[64][65];
  int b = blockIdx.x, t = threadIdx.x;
  if (b < 2048) {  // cvt: 8 independent float4 loads in flight, statically unrolled
    const float4* src = (const float4*)hid;
    uint2* dst = (uint2*)hidc;
    float4 v[8];
#pragma unroll
    for (int c = 0; c < 8; ++c) v[c] = src[(size_t)(b + c * 2048) * 256 + t];
#pragma unroll
    for (int c = 0; c < 8; ++c) {
      uint2 o; o.x = pack2(v[c].x, v[c].y); o.y = pack2(v[c].z, v[c].w);
      dst[(size_t)(b + c * 2048) * 256 + t] = o;
    }
    return;
  }
  b -= 2048;
  if (b < 768) {  // W_hh (1024x3072) -> WgruT cols 512..; col>=2048 remaps +1024
    packT_body(W_hh, 3072, 0, WgruT, 1536, 0, 512, 2048, 1024, 1.f, b % 48, b / 48, tile, t);
    return;
  }
  b -= 768;
  if (b < 384) {  // W_ih rows 0..511 -> WgruT cols 0..511
    packT_body(W_ih, 3072, 0, WgruT, 1536, 0, 0, 1 << 30, 0, 1.f, b % 48, b / 48, tile, t);
    return;
  }
  b -= 384;
  if (b < 32) { packT_body(Wa1, 128, 512, W1catT, 1024, 0, 0, 1 << 30, 0, 1.f, b % 2, b / 2, tile, t); return; }
  b -= 32;
  if (b < 32) { packT_body(Wg1, 128, 512, W1catT, 1024, 128, 0, 1 << 30, 0, 1.f, b % 2, b / 2, tile, t); return; }
  b -= 32;
  if (b < 16) { packT_body(Wa2, 512, 0, W2catT, 256, 0, 0, 1 << 30, 0, 1.f, b % 8, b / 8, tile, t); return; }
  b -= 16;
  if (b < 16) { packT_body(Wg2, 512, 0, W2catT, 256, 0, 128, 1 << 30, 0, -1.f, b % 8, b / 8, tile, t); return; }
  b -= 16;
  if (b < 8) {  // bias1, k-split over 8 blocks, atomic into zeroed buf
    const float* W = (t < 128) ? Wa1 : Wg1;
    int cc = t & 127;
    float acc = 0.f;
    int k0 = b * 64;
    for (int k = k0; k < k0 + 64; ++k) acc += x[k] * W[(size_t)k * 128 + cc];
    if (b == 0) acc += (t < 128) ? ba1[cc] : bg1[cc];
    atomicAdd(&bias1[t], acc);
    return;
  }
  b -= 8;
  if (b < 2) { int n = b * 256 + t; bias2[n] = ba2[n] - bg2[n]; return; }
  b -= 2;
  {
    int i = b * 256 + t;
    int p = positions[i], f = i >> 11;
    if (p > 0) atomicAdd(&counts[f * 2], 1);
    else if (p < 0) atomicAdd(&counts[f * 2 + 1], 1);
  }
}

// =====================================================================
// bf16 MFMA GEMM, 128x128, BK=32, XOR-swizzled LDS (slot = q ^ ((row>>1)&3)).
// Triple-buffered, depth-2 prefetch, counted vmcnt. epi 1: +bias,relu ;
// epi 3: +bias + fused per-row sum-of-squares -> tension.
// =====================================================================
__global__ __launch_bounds__(256) void gemm_bt(
    const u16* __restrict__ A, int lda,
    const u16* __restrict__ Bt, int ldb,
    u16* __restrict__ C, int ldc,
    const float* __restrict__ bias, int epi, int K,
    float* __restrict__ tension) {
  __shared__ __align__(16) u16 As[3][128 * 32];
  __shared__ __align__(16) u16 Bs[3][128 * 32];
  const int tid = threadIdx.x;
  const int m0 = blockIdx.x * 128;
  const int n0 = blockIdx.y * 128;
  f32x4 acc[4][4] = {};
  const int lane = tid & 63;
  const int w = tid >> 6;
  const int mw = (w & 1) * 64, nw = (w >> 1) * 64;
  const int fr = lane & 15;
  const int q = lane >> 4;
  const int ar0 = tid >> 2;                     // rows 0..63 (chunk tid), +64 for chunk tid+256
  const int ag = ((tid & 3) ^ ((ar0 >> 1) & 3)) * 8;  // (row+64)>>1 keeps same &3 -> ag reused

  const u16* aB0 = A + (size_t)(m0 + ar0) * lda + ag;
  const u16* aB1 = A + (size_t)(m0 + ar0 + 64) * lda + ag;
  const u16* bB0 = Bt + (size_t)(n0 + ar0) * ldb + ag;
  const u16* bB1 = Bt + (size_t)(n0 + ar0 + 64) * ldb + ag;

  auto stage = [&](int kk, int buf) {
    __builtin_amdgcn_global_load_lds(AS1(aB0 + kk), AS3(&As[buf][tid * 8]), 16, 0, 0);
    __builtin_amdgcn_global_load_lds(AS1(aB1 + kk), AS3(&As[buf][(tid + 256) * 8]), 16, 0, 0);
    __builtin_amdgcn_global_load_lds(AS1(bB0 + kk), AS3(&Bs[buf][tid * 8]), 16, 0, 0);
    __builtin_amdgcn_global_load_lds(AS1(bB1 + kk), AS3(&Bs[buf][(tid + 256) * 8]), 16, 0, 0);
  };

  const int NT = K >> 5;   // >= 8 for all calls
  stage(0, 0);
  stage(32, 1);
  int cur = 0, nxt = 1, nx2 = 2;
#pragma unroll 1
  for (int t = 0; t < NT; ++t) {
    if (t + 2 < NT) stage((t + 2) * 32, nx2);
    const int rem = NT - 1 - t;  // tiles newer than t in flight
    if (rem >= 2)      asm volatile("s_waitcnt vmcnt(8)" ::: "memory");
    else if (rem == 1) asm volatile("s_waitcnt vmcnt(4)" ::: "memory");
    else               asm volatile("s_waitcnt vmcnt(0)" ::: "memory");
    __builtin_amdgcn_s_barrier();          // tile t fully in LDS (all waves)
    asm volatile("" ::: "memory");
    bf16x8 af[4], bfv[4];
#pragma unroll
    for (int mt = 0; mt < 4; ++mt) {
      int r = mw + mt * 16 + fr;
      af[mt] = *reinterpret_cast<const bf16x8*>(&As[cur][r * 32 + ((q ^ ((r >> 1) & 3)) * 8)]);
    }
#pragma unroll
    for (int nt = 0; nt < 4; ++nt) {
      int r = nw + nt * 16 + fr;
      bfv[nt] = *reinterpret_cast<const bf16x8*>(&Bs[cur][r * 32 + ((q ^ ((r >> 1) & 3)) * 8)]);
    }
    __builtin_amdgcn_s_setprio(1);
#pragma unroll
    for (int mt = 0; mt < 4; ++mt)
#pragma unroll
      for (int nt = 0; nt < 4; ++nt)
        acc[mt][nt] = __builtin_amdgcn_mfma_f32_16x16x32_bf16(af[mt], bfv[nt], acc[mt][nt], 0, 0, 0);
    __builtin_amdgcn_s_setprio(0);
    asm volatile("s_waitcnt lgkmcnt(0)" ::: "memory");  // my ds_reads retired
    __builtin_amdgcn_s_barrier();          // buf[cur] safe to overwrite at t+1
    int tmp = cur; cur = nxt; nxt = nx2; nx2 = tmp;
  }
  const int rq = q * 4;  // D: col=lane&15, row=rq+reg [m89]
#pragma unroll
  for (int mt = 0; mt < 4; ++mt) {
    float srow[4] = {0.f, 0.f, 0.f, 0.f};
#pragma unroll
    for (int nt = 0; nt < 4; ++nt) {
      int col = n0 + nw + nt * 16 + fr;
      f32x4 v = acc[mt][nt];
#pragma unroll
      for (int r = 0; r < 4; ++r) {
        int row = m0 + mw + mt * 16 + rq + r;
        float val = v[r] + bias[col];
        if (epi == 1) val = val > 0.f ? val : 0.f;
        else srow[r] += val * val;
        C[(size_t)row * ldc + col] = f2bf(val);
      }
    }
    if (epi == 3) {
#pragma unroll
      for (int r = 0; r < 4; ++r) {
        float s = srow[r];
        s += __shfl_xor(s, 1, 16); s += __shfl_xor(s, 2, 16);
        s += __shfl_xor(s, 4, 16); s += __shfl_xor(s, 8, 16);
        if (fr == 0) atomicAdd(&tension[m0 + mw + mt * 16 + rq + r], s);
      }
    }
  }
}

// =====================================================================
// R7 fused GRU. 256 threads / 4 waves; block tile 128 rows x 64 j-cols x
// 4 regions; BK=64; wave = 64 rows x 32 j x 4 reg (acc[4][4][2] = 128 VGPR).
// LDS: dbuf As[2][128][64] (32KB) + Bs[2][3][64][64] (48KB) = 80KB -> 2 blk/CU.
// Two independent blocks per CU decouple barriers (m114 overlap mechanism).
// Layout [row][64] u16: slot' = slot ^ (row&7) via pre-swizzled global source.
// Per K-tile: ds ks0 | 24 MFMA | ds ks1 | lgkm0+bar | stage t+2 (10 gld)
// | 24 MFMA | vmcnt(10)+bar. Counted vmcnt in steady state (T3+T4).
// Tiles 0..7: A=outbf (K 0..511), reg3=gi_n(rows 2048+). Tiles 8..23: A=hidc,
// reg3=gh_n(rows 3072+). WgruT k index = s*64 uniformly.
// =====================================================================
__global__ __launch_bounds__(256, 2) void gemm_gru(
    const u16* __restrict__ outbf, const u16* __restrict__ hidc,
    const u16* __restrict__ WgruT,
    const float* __restrict__ W_ihf, const float* __restrict__ bihf,
    const float* __restrict__ bhhf, const float* __restrict__ wealthf,
    const float* __restrict__ tension, u16* __restrict__ hpre) {
  __shared__ __align__(16) u16 As[2][128 * 64];
  __shared__ __align__(16) u16 Bs[2][3][64 * 64];
  const int tid = threadIdx.x;
  const int m0 = blockIdx.x * 128;
  const int j0 = blockIdx.y * 64;
  f32x4 acc[4][4][2] = {};  // [region][mt][nt]
  const int lane = tid & 63;
  const int w = tid >> 6;
  const int mw = (w & 1) * 64, jw = (w >> 1) * 32;
  const int fr = lane & 15;
  const int q = lane >> 4;
  // staging: chunk = tid (row = tid>>3 in [0,32), slot = tid&7); extra rows via
  // +32*it (keeps row&7). global source k-group pre-swizzled: gslot = slot^(row&7).
  const int rowl = tid >> 3;
  const int koffT = ((tid & 7) ^ (rowl & 7)) * 8;
  const size_t aOutB = (size_t)(m0 + rowl) * 512 + koffT;
  const size_t aHidB = (size_t)(m0 + rowl) * 1024 + koffT;
  const size_t bB    = (size_t)(j0 + rowl) * 1536 + koffT;
  // frag-read slot offsets (u16): slot' = (ks*4+q)^(fr&7), *8 elems
  const int f7 = fr & 7;
  const int sk0 = (q ^ f7) * 8;
  const int sk1 = ((4 + q) ^ f7) * 8;

#define STAGE(S, BUF)                                                                              \
  {                                                                                                \
    const size_t kO = (size_t)(S) * 64;                                                            \
    if ((S) < 8) {                                                                                 \
      _Pragma("unroll") for (int it = 0; it < 4; ++it)                                             \
          __builtin_amdgcn_global_load_lds(AS1(outbf + aOutB + (size_t)(32 * it) * 512 + kO),      \
                                           AS3(&As[BUF][tid * 8 + it * 2048]), 16, 0, 0);          \
    } else {                                                                                       \
      const size_t kO1 = (size_t)((S) - 8) * 64;                                                   \
      _Pragma("unroll") for (int it = 0; it < 4; ++it)                                             \
          __builtin_amdgcn_global_load_lds(AS1(hidc + aHidB + (size_t)(32 * it) * 1024 + kO1),     \
                                           AS3(&As[BUF][tid * 8 + it * 2048]), 16, 0, 0);          \
    }                                                                                              \
    const u16* bp = WgruT + bB + kO;                                                               \
    __builtin_amdgcn_global_load_lds(AS1(bp), AS3(&Bs[BUF][0][tid * 8]), 16, 0, 0);                \
    __builtin_amdgcn_global_load_lds(AS1(bp + (size_t)32 * 1536),                                  \
                                     AS3(&Bs[BUF][0][tid * 8 + 2048]), 16, 0, 0);                  \
    __builtin_amdgcn_global_load_lds(AS1(bp + (size_t)1024 * 1536),                                \
                                     AS3(&Bs[BUF][1][tid * 8]), 16, 0, 0);                         \
    __builtin_amdgcn_global_load_lds(AS1(bp + (size_t)1056 * 1536),                                \
                                     AS3(&Bs[BUF][1][tid * 8 + 2048]), 16, 0, 0);                  \
    const size_t nOff = ((S) < 8 ? (size_t)2048 * 1536 : (size_t)3072 * 1536);                     \
    __builtin_amdgcn_global_load_lds(AS1(bp + nOff), AS3(&Bs[BUF][2][tid * 8]), 16, 0, 0);         \
    __builtin_amdgcn_global_load_lds(AS1(bp + nOff + (size_t)32 * 1536),                           \
                                     AS3(&Bs[BUF][2][tid * 8 + 2048]), 16, 0, 0);                  \
  }

#define GRU_STEP(T, REG3, CUR)                                                                     \
  {                                                                                                \
    bf16x8 af0[4], b00[2], b10[2], b20[2];                                                         \
    _Pragma("unroll") for (int mt = 0; mt < 4; ++mt)                                               \
        af0[mt] = *reinterpret_cast<const bf16x8*>(&As[CUR][(mw + mt * 16 + fr) * 64 + sk0]);      \
    _Pragma("unroll") for (int nt = 0; nt < 2; ++nt) {                                             \
      int rj = (jw + nt * 16 + fr) * 64 + sk0;                                                     \
      b00[nt] = *reinterpret_cast<const bf16x8*>(&Bs[CUR][0][rj]);                                 \
      b10[nt] = *reinterpret_cast<const bf16x8*>(&Bs[CUR][1][rj]);                                 \
      b20[nt] = *reinterpret_cast<const bf16x8*>(&Bs[CUR][2][rj]);                                 \
    }                                                                                              \
    __builtin_amdgcn_s_setprio(1);                                                                 \
    _Pragma("unroll") for (int mt = 0; mt < 4; ++mt)                                               \
        _Pragma("unroll") for (int nt = 0; nt < 2; ++nt) {                                         \
      acc[0][mt][nt] = __builtin_amdgcn_mfma_f32_16x16x32_bf16(af0[mt], b00[nt], acc[0][mt][nt], 0, 0, 0); \
      acc[1][mt][nt] = __builtin_amdgcn_mfma_f32_16x16x32_bf16(af0[mt], b10[nt], acc[1][mt][nt], 0, 0, 0); \
      acc[REG3][mt][nt] = __builtin_amdgcn_mfma_f32_16x16x32_bf16(af0[mt], b20[nt], acc[REG3][mt][nt], 0, 0, 0); \
    }                                                                                              \
    __builtin_amdgcn_s_setprio(0);                                                                 \
    bf16x8 af1[4], b01[2], b11[2], b21[2];                                                         \
    _Pragma("unroll") for (int mt = 0; mt < 4; ++mt)                                               \
        af1[mt] = *reinterpret_cast<const bf16x8*>(&As[CUR][(mw + mt * 16 + fr) * 64 + sk1]);      \
    _Pragma("unroll") for (int nt = 0; nt < 2; ++nt) {                                             \
      int rj = (jw + nt * 16 + fr) * 64 + sk1;                                                     \
      b01[nt] = *reinterpret_cast<const bf16x8*>(&Bs[CUR][0][rj]);                                 \
      b11[nt] = *reinterpret_cast<const bf16x8*>(&Bs[CUR][1][rj]);                                 \
      b21[nt] = *reinterpret_cast<const bf16x8*>(&Bs[CUR][2][rj]);                                 \
    }                                                                                              \
    asm volatile("s_waitcnt lgkmcnt(0)" ::: "memory");                                             \
    __builtin_amdgcn_s_barrier();                                                                  \
    asm volatile("" ::: "memory");                                                                 \
    if ((T) + 2 < 24) { STAGE((T) + 2, CUR) }                                                      \
    __builtin_amdgcn_s_setprio(1);                                                                 \
    _Pragma("unroll") for (int mt = 0; mt < 4; ++mt)                                               \
        _Pragma("unroll") for (int nt = 0; nt < 2; ++nt) {                                         \
      acc[0][mt][nt] = __builtin_amdgcn_mfma_f32_16x16x32_bf16(af1[mt], b01[nt], acc[0][mt][nt], 0, 0, 0); \
      acc[1][mt][nt] = __builtin_amdgcn_mfma_f32_16x16x32_bf16(af1[mt], b11[nt], acc[1][mt][nt], 0, 0, 0); \
      acc[REG3][mt][nt] = __builtin_amdgcn_mfma_f32_16x16x32_bf16(af1[mt], b21[nt], acc[REG3][mt][nt], 0, 0, 0); \
    }                                                                                              \
    __builtin_amdgcn_s_setprio(0);                                                                 \
    if ((T) + 2 < 24)      { asm volatile("s_waitcnt vmcnt(10)" ::: "memory"); }                   \
    else if ((T) + 1 < 24) { asm volatile("s_waitcnt vmcnt(0)" ::: "memory"); }                    \
    __builtin_amdgcn_s_barrier();                                                                  \
    asm volatile("" ::: "memory");                                                                 \
  }

  STAGE(0, 0)
  STAGE(1, 1)
  asm volatile("s_waitcnt vmcnt(10)" ::: "memory");
  __builtin_amdgcn_s_barrier();
  asm volatile("" ::: "memory");
#pragma unroll 1
  for (int T = 0; T < 8; T += 2) {   // tiles 0..7: reg3 = gi_n
    GRU_STEP(T, 2, 0)
    GRU_STEP(T + 1, 2, 1)
  }
#pragma unroll 1
  for (int T = 8; T < 24; T += 2) {  // tiles 8..23: reg3 = gh_n
    GRU_STEP(T, 3, 0)
    GRU_STEP(T + 1, 3, 1)
  }
#undef GRU_STEP
#undef STAGE

  // epilogue: D col=lane&15, row=(lane>>4)*4+reg [m89]
  const int rq = q * 4;
  const float* wt = W_ihf + (size_t)512 * 3072;  // tension row
  float wtr[2], wtz[2], wtn[2], bir[2], biz[2], bin_[2], bhr_[2], bhz_[2], bhn_[2];
#pragma unroll
  for (int nt = 0; nt < 2; ++nt) {
    int j = j0 + jw + nt * 16 + fr;
    wtr[nt] = wt[j]; wtz[nt] = wt[1024 + j]; wtn[nt] = wt[2048 + j];
    bir[nt] = bihf[j]; biz[nt] = bihf[1024 + j]; bin_[nt] = bihf[2048 + j];
    bhr_[nt] = bhhf[j]; bhz_[nt] = bhhf[1024 + j]; bhn_[nt] = bhhf[2048 + j];
  }
#pragma unroll
  for (int mt = 0; mt < 4; ++mt) {
#pragma unroll
    for (int rr = 0; rr < 4; ++rr) {
      int row = m0 + mw + mt * 16 + rq + rr;
      float tv = tension[row] * (1.f / 512.f);
      float wl = fminf(fmaxf(wealthf[row], 0.1f), 2.0f);
      float mod = 0.9f + 0.1f * wl;
#pragma unroll
      for (int nt = 0; nt < 2; ++nt) {
        int j = j0 + jw + nt * 16 + fr;
        float r = sigm(acc[0][mt][nt][rr] + tv * wtr[nt] + bir[nt] + bhr_[nt]);
        float z = sigm(acc[1][mt][nt][rr] + tv * wtz[nt] + biz[nt] + bhz_[nt]);
        float n = fast_tanh(acc[2][mt][nt][rr] + tv * wtn[nt] + bin_[nt]
                            + r * (acc[3][mt][nt][rr] + bhn_[nt]));
        float h = bf2f(hidc[(size_t)row * 1024 + j]);
        float h2 = (1.f - z) * n + z * h;
        h2 = fminf(fmaxf(h2 * mod, -10.f), 10.f);
        hpre[(size_t)row * 1024 + j] = f2bf(h2);
      }
    }
  }
}

// =====================================================================
__global__ void stats_kernel(const u16* __restrict__ hpre, const int* __restrict__ positions,
                             float* __restrict__ fsums) {
  int cc = blockIdx.x, f = blockIdx.y, z = blockIdx.z, t = threadIdx.x;
  int col = cc * 128 + (t & 127);
  int half = t >> 7;
  float st = 0, sp = 0, sm = 0;
  for (int it = 0; it < 128; ++it) {
    int row = (f << 11) + ((z * 128 + it) << 1) + half;
    int p = positions[row];
    float v = bf2f(hpre[(size_t)row * 1024 + col]);
    st += v;
    if (p > 0) sp += v;
    if (p < 0) sm += v;
  }
  atomicAdd(&fsums[(f * 3 + 0) * 1024 + col], st);
  atomicAdd(&fsums[(f * 3 + 1) * 1024 + col], sp);
  atomicAdd(&fsums[(f * 3 + 2) * 1024 + col], sm);
}

__global__ void derive_kernel(const float* __restrict__ fsums, const int* __restrict__ counts,
                              float* __restrict__ mean1, float* __restrict__ mean2,
                              float* __restrict__ fmean, float* __restrict__ gop,
                              float* __restrict__ scal) {
  int c = threadIdx.x;  // 1024
  int cnt1 = 0, cnt2 = 0, cf1[8], cf2[8];
#pragma unroll
  for (int f = 0; f < 8; ++f) {
    cf1[f] = counts[f * 2]; cf2[f] = counts[f * 2 + 1];
    cnt1 += cf1[f]; cnt2 += cf2[f];
  }
  float s1 = 0, s2 = 0;
#pragma unroll
  for (int f = 0; f < 8; ++f) { s1 += fsums[(f * 3 + 1) * 1024 + c]; s2 += fsums[(f * 3 + 2) * 1024 + c]; }
  float m1 = s1 / (float)(cnt1 > 1 ? cnt1 : 1);
  float m2 = s2 / (float)(cnt2 > 1 ? cnt2 : 1);
  float a1 = (cnt1 >= 2) ? 0.1f : 0.f;
  float a2 = (cnt2 >= 2) ? 0.1f : 0.f;
  float g = 0;
#pragma unroll
  for (int f = 0; f < 8; ++f) {
    float fm = (fsums[(f * 3) * 1024 + c]
                + a1 * ((float)cf1[f] * m1 - fsums[(f * 3 + 1) * 1024 + c])
                + a2 * ((float)cf2[f] * m2 - fsums[(f * 3 + 2) * 1024 + c])) * (1.f / 2048.f);
    fmean[f * 1024 + c] = fm;
    g += fm;
  }
  gop[c] = g * 0.125f;
  mean1[c] = m1; mean2[c] = m2;
  if (c == 0) { scal[0] = a1; scal[1] = a2; }
}

// R8: 2048 blocks x 256 thr; block handles 8 rows x 1024 cols (4 col-slices).
__global__ void finalize_kernel(const u16* __restrict__ hpre, const int* __restrict__ positions,
                                const int* __restrict__ step, const float* __restrict__ mean1,
                                const float* __restrict__ mean2, const float* __restrict__ fmean,
                                const float* __restrict__ gop, const float* __restrict__ scal,
                                float* __restrict__ out) {
  int t = threadIdx.x;
  int r0 = blockIdx.x * 8;
  float s0 = scal[0], s1 = scal[1];
  bool step5 = step[0] > 5;
#pragma unroll 2
  for (int rr = 0; rr < 8; ++rr) {
    int row = r0 + rr;
    int p = positions[row];
    float w1 = (p > 0) ? s0 : 0.f;
    float w2 = (p < 0) ? s1 : 0.f;
    int f = row >> 11, qq = row & 2047;
    bool deb = step5 && (qq < 512);
    const u16* hrow = hpre + (size_t)row * 1024;
    const float* fmp = fmean + f * 1024;
    float* orow = out + 513 + (size_t)row * 1024;
#pragma unroll
    for (int e = 0; e < 4; ++e) {
      int c = e * 256 + t;
      float h = bf2f(hrow[c]);
      float hgs = h + w1 * (mean1[c] - h) + w2 * (mean2[c] - h);
      float hfs = 0.85f * hgs + 0.15f * fmp[c];
      orow[c] = deb ? (0.85f * hfs + 0.15f * gop[c]) : hfs;
    }
  }
}

__global__ void softmax_kernel(const float* __restrict__ tension, float* __restrict__ weights,
                               float* __restrict__ out) {
  __shared__ float red[1024];
  int t = threadIdx.x;
  float tv[16], mx = -1e30f, sumt = 0.f;
#pragma unroll
  for (int k = 0; k < 16; ++k) {
    tv[k] = tension[t + k * 1024] * (1.f / 512.f);
    mx = fmaxf(mx, tv[k]); sumt += tv[k];
  }
  red[t] = mx; __syncthreads();
  for (int s = 512; s > 0; s >>= 1) { if (t < s) red[t] = fmaxf(red[t], red[t + s]); __syncthreads(); }
  float m = red[0]; __syncthreads();
  red[t] = sumt; __syncthreads();
  for (int s = 512; s > 0; s >>= 1) { if (t < s) red[t] += red[t + s]; __syncthreads(); }
  float tot = red[0]; __syncthreads();
  float ev[16], se = 0.f;
#pragma unroll
  for (int k = 0; k < 16; ++k) { ev[k] = __expf(tv[k] - m); se += ev[k]; }
  red[t] = se; __syncthreads();
  for (int s = 512; s > 0; s >>= 1) { if (t < s) red[t] += red[t + s]; __syncthreads(); }
  float invS = 1.f / red[0];
#pragma unroll
  for (int k = 0; k < 16; ++k) weights[t + k * 1024] = ev[k] * invS;
  if (t == 0) out[512] = tot * (1.f / 16384.f);
}

__global__ void wsum_kernel(const float* __restrict__ weights, const u16* __restrict__ outbf,
                            float* __restrict__ co) {
  int b = blockIdx.x, t = threadIdx.x;
  int c = t * 2;
  float a0 = 0.f, a1 = 0.f;
  int i0 = b * 128;
  for (int i = i0; i < i0 + 128; ++i) {
    float w = weights[i];
    unsigned v = *reinterpret_cast<const unsigned*>(outbf + (size_t)i * 512 + c);
    a0 += w * bf2f(v & 0xffff);
    a1 += w * bf2f(v >> 16);
  }
  atomicAdd(&co[c], a0);
  atomicAdd(&co[c + 1], a1);
}

__global__ void pred_kernel(const float* __restrict__ co, const float* __restrict__ Wof,
                            const float* __restrict__ bof, float* __restrict__ out) {
  __shared__ float cs[512];
  int t = threadIdx.x, n = blockIdx.x * 256 + t;
  cs[t] = co[t]; cs[t + 256] = co[t + 256];
  __syncthreads();
  float acc = bof[n];
  for (int ck = 0; ck < 512; ++ck) acc += cs[ck] * Wof[(size_t)ck * 512 + n];
  out[n] = acc;
}

// =====================================================================
extern "C" void kernel_launch(void* const* d_in, const int* in_sizes, int n_in,
                              void* d_out, int out_size, void* d_ws, size_t ws_size,
                              hipStream_t stream) {
  const float* x      = (const float*)d_in[0];
  const float* hid    = (const float*)d_in[1];
  const float* wealth = (const float*)d_in[2];
  const float* Wa1    = (const float*)d_in[3];
  const float* ba1    = (const float*)d_in[4];
  const float* Wa2    = (const float*)d_in[5];
  const float* ba2    = (const float*)d_in[6];
  const float* Wg1    = (const float*)d_in[7];
  const float* bg1    = (const float*)d_in[8];
  const float* Wg2    = (const float*)d_in[9];
  const float* bg2    = (const float*)d_in[10];
  const float* W_ih   = (const float*)d_in[11];
  const float* W_hh   = (const float*)d_in[12];
  const float* b_ih   = (const float*)d_in[13];
  const float* b_hh   = (const float*)d_in[14];
  const float* Wo     = (const float*)d_in[15];
  const float* bo     = (const float*)d_in[16];
  const int* positions= (const int*)d_in[17];
  const int* step     = (const int*)d_in[18];
  float* out = (float*)d_out;  // [0,512) pred | [512] avg_tension | [513..) new_h

  char* w = (char*)d_ws;
  size_t off = 0;
  auto alloc = [&](size_t bytes) { void* p = w + off; off += (bytes + 255) & ~(size_t)255; return p; };
  u16*   hidc    = (u16*)  alloc((size_t)NC * 1024 * 2);
  u16*   outbf   = (u16*)  alloc((size_t)NC * 512 * 2);
  u16*   hpre    = (u16*)  alloc((size_t)NC * 1024 * 2);
  u16*   WgruT   = (u16*)  alloc((size_t)4096 * 1536 * 2);
  u16*   W1catT  = (u16*)  alloc((size_t)256 * 1024 * 2);
  u16*   W2catT  = (u16*)  alloc((size_t)512 * 256 * 2);
  u16*   t1      = (u16*)  alloc((size_t)NC * 256 * 2);
  // zeroed contiguous: bias1 | co | counts | fsums | tension
  float* bias1   = (float*)alloc(256 * 4);
  float* co      = (float*)alloc(512 * 4);
  int*   counts  = (int*)  alloc(16 * 4);
  float* fsums   = (float*)alloc(8 * 3 * 1024 * 4);
  float* tension = (float*)alloc(NC * 4);
  float* bias2   = (float*)alloc(512 * 4);
  float* weights = (float*)alloc(NC * 4);
  float* mean1   = (float*)alloc(1024 * 4);
  float* mean2   = (float*)alloc(1024 * 4);
  float* gop     = (float*)alloc(1024 * 4);
  float* fmean   = (float*)alloc(8 * 1024 * 4);
  float* scal    = (float*)alloc(8 * 4);

  hipMemsetAsync(bias1, 0, 1024 + 2048 + 256 + 98304 + 65536, stream);

  // cvt (2048) + packT (1248) + smalls (74)
  prep_kernel<<<3370, 256, 0, stream>>>(hid, hidc, W_ih, W_hh, WgruT,
                                        Wa1, Wg1, W1catT, Wa2, Wg2, W2catT,
                                        x, ba1, bg1, bias1, ba2, bg2, bias2,
                                        positions, counts);

  // t1 = relu(h @ W1 + bias1)   M=16384 K=1024 N=256
  gemm_bt<<<dim3(128, 2), 256, 0, stream>>>(hidc, 1024, W1catT, 1024, t1, 256,
                                            bias1, 1, 1024, nullptr);
  // output = t1 @ [Wa2;-Wg2] + (ba2-bg2); fused tension
  gemm_bt<<<dim3(128, 4), 256, 0, stream>>>(t1, 256, W2catT, 256, outbf, 512,
                                            bias2, 3, 256, tension);

  // fused GRU (128x64 tiles, 2048 blocks, 256 threads, 2 blocks/CU)
  gemm_gru<<<dim3(128, 16), 256, 0, stream>>>(outbf, hidc, WgruT, W_ih, b_ih, b_hh,
                                              wealth, tension, hpre);

  stats_kernel<<<dim3(8, 8, 8), 256, 0, stream>>>(hpre, positions, fsums);
  derive_kernel<<<1, 1024, 0, stream>>>(fsums, counts, mean1, mean2, fmean, gop, scal);
  finalize_kernel<<<2048, 256, 0, stream>>>(hpre, positions, step, mean1, mean2, fmean, gop,
                                            scal, out);

  softmax_kernel<<<1, 1024, 0, stream>>>(tension, weights, out);
  wsum_kernel<<<128, 256, 0, stream>>>(weights, outbf, co);
  pred_kernel<<<2, 256, 0, stream>>>(co, Wo, bo, out);

  (void)in_sizes; (void)n_in; (void)out_size; (void)ws_size;
}